// Round 4
// baseline (491.602 us; speedup 1.0000x reference)
//
#include <hip/hip_runtime.h>

#define N_NODES 80000
#define N_EDGES 64000
#define NB      32
#define NG      2500
#define NA      50
#define EDIM    16
#define FIN     159      // H2(64) + AF(95)
#define HG      128
#define RICOLS  2688     // 21 blocks of 128: 18 root(t,k) + 3 init(k)

typedef __attribute__((ext_vector_type(8))) short bf16x8;
typedef __attribute__((ext_vector_type(4))) float f32x4;

__device__ inline ushort rne_bf16(float f) {
    union { float f; unsigned u; } v; v.f = f;
    const unsigned r = v.u + 0x7fffu + ((v.u >> 16) & 1u);
    return (ushort)(r >> 16);
}
__device__ inline float bf16_to_f32(ushort h) {
    union { unsigned u; float f; } v; v.u = ((unsigned)h) << 16;
    return v.f;
}

// ---------------- weight prep: w_e[16,64*64]+b_e[4096] -> bf16 hi/lo fragments ----------------
// Fragment order: Wt[((j*8 + n*2 + kq)*64 + lane)*8 + t] = bf16(W[j][i][o]),
//   o = n*16 + (lane&15), i = kq*32 + (lane>>4)*8 + t   (j==16 -> b_e)
__global__ __launch_bounds__(256) void prep_w(const float* __restrict__ we,
    const float* __restrict__ be, ushort* __restrict__ Whi, ushort* __restrict__ Wlo)
{
    const int idx = blockIdx.x * 256 + threadIdx.x;
    if (idx >= 17 * 8 * 64) return;
    const int l = idx & 63;
    const int slot = (idx >> 6) & 7;
    const int j = idx >> 9;
    const int n = slot >> 1, kq = slot & 1;
    const int o = n * 16 + (l & 15);
    const int i0 = kq * 32 + (l >> 4) * 8;
    ushort th[8], tl[8];
#pragma unroll
    for (int t = 0; t < 8; ++t) {
        const int i = i0 + t;
        const float f = (j < 16) ? we[j * 4096 + i * 64 + o] : be[i * 64 + o];
        const ushort hi = rne_bf16(f);
        th[t] = hi;
        tl[t] = rne_bf16(f - bf16_to_f32(hi));
    }
    *(uint4*)(Whi + (size_t)idx * 8) = *(const uint4*)th;
    *(uint4*)(Wlo + (size_t)idx * 8) = *(const uint4*)tl;
}

// ---------------- root GEMM: out[n,:] = relu?(in[n,:]) @ W(64x64) + bias ----------------
template<int RELU>
__global__ __launch_bounds__(256) void root_gemm(const float* __restrict__ in,
    const float* __restrict__ w, const float* __restrict__ bias, float* __restrict__ out)
{
    __shared__ float At[64 * 65];   // At[c*65 + r]
    __shared__ float Wl[64 * 64];   // [i*64 + o]
    __shared__ float bl[64];
    const int tid = threadIdx.x;
    const int r0 = blockIdx.x * 64;
    for (int s = tid; s < 4096; s += 256) {
        int r = s >> 6, c = s & 63;
        float v = in[(r0 + r) * 64 + c];
        if (RELU) v = fmaxf(v, 0.f);
        At[c * 65 + r] = v;
    }
    for (int s = tid; s < 4096; s += 256) Wl[s] = w[s];
    if (tid < 64) bl[tid] = bias[tid];
    __syncthreads();
    const int tr = tid >> 4, tc = tid & 15;
    float acc[4][4] = {};
#pragma unroll 8
    for (int i = 0; i < 64; ++i) {
        const float4 a4 = *(const float4*)&At[i * 65 + tr * 4];
        const float4 b4 = *(const float4*)&Wl[i * 64 + tc * 4];
        const float av[4] = {a4.x, a4.y, a4.z, a4.w};
        const float bv[4] = {b4.x, b4.y, b4.z, b4.w};
#pragma unroll
        for (int m = 0; m < 4; ++m)
#pragma unroll
            for (int n = 0; n < 4; ++n) acc[m][n] = fmaf(av[m], bv[n], acc[m][n]);
    }
    const float4 bq = *(const float4*)&bl[tc * 4];
#pragma unroll
    for (int m = 0; m < 4; ++m) {
        float4 o4 = {acc[m][0] + bq.x, acc[m][1] + bq.y, acc[m][2] + bq.z, acc[m][3] + bq.w};
        *(float4*)&out[(r0 + tr * 4 + m) * 64 + tc * 4] = o4;
    }
}

// ---------------- NNConv edge kernel, bf16x3 MFMA, TE=64, B staged in LDS ----------------
// msg[e,o] = sum_j ea'[e,j] * (relu?(H[src_e,:]) @ Wj)[o]
#define TE 64
template<int RELU>
__global__ __launch_bounds__(256) void edge_conv_mfma(const float* __restrict__ h,
    const float* __restrict__ ea, const int* __restrict__ src, const int* __restrict__ dst,
    const ushort* __restrict__ Whi, const ushort* __restrict__ Wlo, float* __restrict__ agg)
{
    __shared__ ushort Bst[2][8192];     // per buf: hi frags [0,4096), lo frags [4096,8192)
    __shared__ float  EAt[17 * 68];     // [j][edge]
    const int tid = threadIdx.x;
    const int e0 = blockIdx.x * TE;
    const int wv = tid >> 6, l = tid & 63;

    // stage edge attrs [j][e] (+ 1.0 row for bias)
    for (int s = tid; s < TE * 16; s += 256) {
        const int le = s >> 4, j = s & 15;
        EAt[j * 68 + le] = ea[(long)(e0 + le) * 16 + j];
    }
    if (tid < TE) EAt[16 * 68 + tid] = 1.0f;

    // stage B(j=0) into buf 0
    {
        const uint4* shv = (const uint4*)Whi;
        const uint4* slv = (const uint4*)Wlo;
        uint4* dh = (uint4*)&Bst[0][0];
        uint4* dl = (uint4*)&Bst[0][4096];
        dh[tid * 2]     = shv[tid * 2];
        dh[tid * 2 + 1] = shv[tid * 2 + 1];
        dl[tid * 2]     = slv[tid * 2];
        dl[tid * 2 + 1] = slv[tid * 2 + 1];
    }

    // gather A fragments (each lane: one edge row, 64 features) hi/lo in registers
    const int row16 = l & 15;
    const int sidx = src[e0 + wv * 16 + row16];
    bf16x8 ah[2], al[2];
    {
        const float4* hp = (const float4*)(h + (long)sidx * 64);
#pragma unroll
        for (int kq = 0; kq < 2; ++kq) {
            const int q0 = (kq * 32 + (l >> 4) * 8) >> 2;
            float4 v0 = hp[q0], v1 = hp[q0 + 1];
            float fv[8] = {v0.x, v0.y, v0.z, v0.w, v1.x, v1.y, v1.z, v1.w};
            ushort th[8], tl[8];
#pragma unroll
            for (int t = 0; t < 8; ++t) {
                float f = RELU ? fmaxf(fv[t], 0.f) : fv[t];
                th[t] = rne_bf16(f);
                tl[t] = rne_bf16(f - bf16_to_f32(th[t]));
            }
            ah[kq] = *(const bf16x8*)th;
            al[kq] = *(const bf16x8*)tl;
        }
    }
    __syncthreads();

    f32x4 msg[4];
#pragma unroll
    for (int n = 0; n < 4; ++n) msg[n] = (f32x4)0.f;

#pragma unroll 1
    for (int j = 0; j < 17; ++j) {
        const int cur = j & 1;
        // issue next-j B loads early (regs), write after barrier
        uint4 rh[2], rl[2];
        if (j < 16) {
            const uint4* shv = (const uint4*)(Whi + (size_t)(j + 1) * 4096);
            const uint4* slv = (const uint4*)(Wlo + (size_t)(j + 1) * 4096);
            rh[0] = shv[tid * 2]; rh[1] = shv[tid * 2 + 1];
            rl[0] = slv[tid * 2]; rl[1] = slv[tid * 2 + 1];
        }
        // compute j
        const f32x4 eam = *(const f32x4*)&EAt[j * 68 + wv * 16 + (l >> 4) * 4];
#pragma unroll
        for (int n = 0; n < 4; ++n) {
            const bf16x8 bh0 = *(const bf16x8*)&Bst[cur][((n * 2 + 0) * 64 + l) * 8];
            const bf16x8 bh1 = *(const bf16x8*)&Bst[cur][((n * 2 + 1) * 64 + l) * 8];
            const bf16x8 bl0 = *(const bf16x8*)&Bst[cur][4096 + ((n * 2 + 0) * 64 + l) * 8];
            const bf16x8 bl1 = *(const bf16x8*)&Bst[cur][4096 + ((n * 2 + 1) * 64 + l) * 8];
            f32x4 t = __builtin_amdgcn_mfma_f32_16x16x32_bf16(ah[0], bh0, (f32x4)0.f, 0, 0, 0);
            t = __builtin_amdgcn_mfma_f32_16x16x32_bf16(ah[1], bh1, t, 0, 0, 0);
            t = __builtin_amdgcn_mfma_f32_16x16x32_bf16(ah[0], bl0, t, 0, 0, 0);
            t = __builtin_amdgcn_mfma_f32_16x16x32_bf16(ah[1], bl1, t, 0, 0, 0);
            t = __builtin_amdgcn_mfma_f32_16x16x32_bf16(al[0], bh0, t, 0, 0, 0);
            t = __builtin_amdgcn_mfma_f32_16x16x32_bf16(al[1], bh1, t, 0, 0, 0);
            msg[n] += eam * t;
        }
        __syncthreads();
        if (j < 16) {
            uint4* dh = (uint4*)&Bst[cur ^ 1][0];
            uint4* dl = (uint4*)&Bst[cur ^ 1][4096];
            dh[tid * 2] = rh[0]; dh[tid * 2 + 1] = rh[1];
            dl[tid * 2] = rl[0]; dl[tid * 2 + 1] = rl[1];
            __syncthreads();
        }
    }

    // scatter: C/D layout col=l&15 within n-tile, row=(l>>4)*4+r
#pragma unroll
    for (int r = 0; r < 4; ++r) {
        const int erow = wv * 16 + (l >> 4) * 4 + r;
        const long d = dst[e0 + erow];
#pragma unroll
        for (int n = 0; n < 4; ++n) {
            const int col = n * 16 + (l & 15);
            atomicAdd(&agg[d * 64 + col], msg[n][r]);
        }
    }
}

// ---------------- atom attention scores (relu on load) ----------------
__global__ __launch_bounds__(256) void scores_k(const float* __restrict__ h2,
    const float* __restrict__ w, const float* __restrict__ b, float* __restrict__ sc)
{
    __shared__ float wl[64];
    if (threadIdx.x < 64) wl[threadIdx.x] = w[threadIdx.x];
    __syncthreads();
    const int n = blockIdx.x * 256 + threadIdx.x;
    if (n < N_NODES) {
        float acc = b[0];
        const float4* hp = (const float4*)(h2 + (long)n * 64);
#pragma unroll
        for (int q = 0; q < 16; ++q) {
            const float4 v = hp[q];
            acc = fmaf(fmaxf(v.x, 0.f), wl[q * 4 + 0], acc); acc = fmaf(fmaxf(v.y, 0.f), wl[q * 4 + 1], acc);
            acc = fmaf(fmaxf(v.z, 0.f), wl[q * 4 + 2], acc); acc = fmaf(fmaxf(v.w, 0.f), wl[q * 4 + 3], acc);
        }
        sc[n] = acc;
    }
}

// ---------------- per-graph softmax over atoms ----------------
__global__ __launch_bounds__(256) void softmax_k(const float* __restrict__ sc, float* __restrict__ attn)
{
    __shared__ float red[256];
    const int g = blockIdx.x, tid = threadIdx.x;
    const float* s = sc + (long)g * NG;
    float m = -1e30f;
    for (int a = tid; a < NG; a += 256) m = fmaxf(m, s[a]);
    red[tid] = m; __syncthreads();
    for (int st = 128; st; st >>= 1) { if (tid < st) red[tid] = fmaxf(red[tid], red[tid + st]); __syncthreads(); }
    const float mx = red[0]; __syncthreads();
    float sum = 0.f;
    for (int a = tid; a < NG; a += 256) sum += expf(s[a] - mx);
    red[tid] = sum; __syncthreads();
    for (int st = 128; st; st >>= 1) { if (tid < st) red[tid] += red[tid + st]; __syncthreads(); }
    const float inv = 1.0f / red[0];
    for (int a = tid; a < NG; a += 256) attn[(long)g * NG + a] = expf(s[a] - mx) * inv;
}

// ---------------- residue pooling + xi concat (relu on load) ----------------
__global__ __launch_bounds__(256) void amino_k(const float* __restrict__ h2,
    const float* __restrict__ attn, const float* __restrict__ aa, float* __restrict__ xi)
{
    const int tid = threadIdx.x;
    const int r = blockIdx.x * 4 + (tid >> 6);   // global residue 0..1599
    const int o = tid & 63;
    const int g = r / NA, ar = r % NA;
    const long base = (long)g * NG + ar * 50;
    float acc = 0.f;
#pragma unroll 10
    for (int a = 0; a < 50; ++a) acc = fmaf(attn[base + a], fmaxf(h2[(base + a) * 64 + o], 0.f), acc);
    xi[(long)r * FIN + o] = acc;
    for (int s = tid; s < 4 * 95; s += 256) {
        const int lr = s / 95, f = s % 95;
        const int rr = blockIdx.x * 4 + lr;
        xi[(long)rr * FIN + 64 + f] = aa[(long)rr * 95 + f];
    }
}

// ---------------- RI GEMM: [1600,159] @ [159,2688] (+bias on root cols) ----------------
__global__ __launch_bounds__(256) void ri_gemm(const float* __restrict__ xi,
    const float* __restrict__ rootw, const float* __restrict__ initw,
    const float* __restrict__ abias, float* __restrict__ RI)
{
    __shared__ float At[32 * 65];   // [kk*65 + r]
    __shared__ float Bl[32 * 64];   // [kk*64 + cc]
    const int tid = threadIdx.x;
    const int r0 = blockIdx.x * 64, c0 = blockIdx.y * 64;
    const int blk = c0 >> 7;             // 0..20
    const int gb = c0 & 127;             // 0 or 64
    const float* bsrc = (blk < 18) ? (rootw + (long)blk * FIN * 128) : (initw + (long)(blk - 18) * FIN * 128);
    const int tr = tid >> 4, tc = tid & 15;
    float acc[4][4] = {};
    for (int f0 = 0; f0 < FIN; f0 += 32) {
        __syncthreads();
        for (int s = tid; s < 64 * 32; s += 256) {
            const int r = s >> 5, kk = s & 31; const int f = f0 + kk;
            At[kk * 65 + r] = (f < FIN) ? xi[(long)(r0 + r) * FIN + f] : 0.f;
        }
        for (int s = tid; s < 32 * 64; s += 256) {
            const int kk = s >> 6, cc = s & 63; const int f = f0 + kk;
            Bl[s] = (f < FIN) ? bsrc[(long)f * 128 + gb + cc] : 0.f;
        }
        __syncthreads();
#pragma unroll 8
        for (int kk = 0; kk < 32; ++kk) {
            const float4 a4 = *(const float4*)&At[kk * 65 + tr * 4];
            const float4 b4 = *(const float4*)&Bl[kk * 64 + tc * 4];
            const float av[4] = {a4.x, a4.y, a4.z, a4.w};
            const float bv[4] = {b4.x, b4.y, b4.z, b4.w};
#pragma unroll
            for (int m = 0; m < 4; ++m)
#pragma unroll
                for (int n = 0; n < 4; ++n) acc[m][n] = fmaf(av[m], bv[n], acc[m][n]);
        }
    }
    float4 bq = {0.f, 0.f, 0.f, 0.f};
    if (blk < 18) bq = *(const float4*)&abias[c0 + tc * 4];
#pragma unroll
    for (int m = 0; m < 4; ++m) {
        float4 o4 = {acc[m][0] + bq.x, acc[m][1] + bq.y, acc[m][2] + bq.z, acc[m][3] + bq.w};
        *(float4*)&RI[(long)(r0 + tr * 4 + m) * RICOLS + c0 + tc * 4] = o4;
    }
}

// ---------------- ARMA step t: nxt = relu(shift(cur) @ W[t-1,k] + RI_root[t,k]) ----------------
// INIT=1 (t==1): cur is synthesized on the fly from RI (t=0 output), no arma0 pass.
template<int INIT>
__global__ __launch_bounds__(256) void arma_step(const float* __restrict__ cur,
    const float* __restrict__ RI, const float* __restrict__ armaw, float* __restrict__ nxt, int t)
{
    __shared__ float Al[64 * 64];   // [r*64 + ff] (per 64-wide f chunk)
    __shared__ float Bl[64 * 64];   // [ff*64 + cc]
    const int tid = threadIdx.x;
    const int r0 = blockIdx.x * 64, c0 = blockIdx.y * 64, k = blockIdx.z;
    const float* W = armaw + (long)((t - 1) * 3 + k) * 128 * 128;
    const int tr = tid >> 4, tc = tid & 15;
    float acc[4][4] = {};
    for (int f0 = 0; f0 < 128; f0 += 64) {
        __syncthreads();
        for (int s = tid; s < 4096; s += 256) {
            const int r = s >> 6, ff = s & 63;
            const int rr = r0 + r; const int a = rr % NA;
            float v = 0.f;
            if (INIT) {
                if (a >= 2) {
                    v = RI[(long)(rr - 1) * RICOLS + k * 128 + f0 + ff];
                    if (a >= 3) v += RI[(long)(rr - 2) * RICOLS + (18 + k) * 128 + f0 + ff];
                    v = fmaxf(v, 0.f);
                }
            } else {
                if (a >= 2) v = cur[(long)k * 1600 * 128 + (rr - 1) * 128 + f0 + ff];
            }
            Al[s] = v;
        }
        for (int s = tid; s < 4096; s += 256) {
            const int ff = s >> 6, cc = s & 63;
            Bl[s] = W[(long)(f0 + ff) * 128 + c0 + cc];
        }
        __syncthreads();
#pragma unroll 8
        for (int ff = 0; ff < 64; ++ff) {
            const float4 b4 = *(const float4*)&Bl[ff * 64 + tc * 4];
            const float bv[4] = {b4.x, b4.y, b4.z, b4.w};
#pragma unroll
            for (int m = 0; m < 4; ++m) {
                const float av = Al[(tr * 4 + m) * 64 + ff];
#pragma unroll
                for (int n = 0; n < 4; ++n) acc[m][n] = fmaf(av, bv[n], acc[m][n]);
            }
        }
    }
#pragma unroll
    for (int m = 0; m < 4; ++m) {
        const int rr = r0 + tr * 4 + m;
        const float4 rq = *(const float4*)&RI[(long)rr * RICOLS + (t * 3 + k) * 128 + c0 + tc * 4];
        float4 o4 = {fmaxf(acc[m][0] + rq.x, 0.f), fmaxf(acc[m][1] + rq.y, 0.f),
                     fmaxf(acc[m][2] + rq.z, 0.f), fmaxf(acc[m][3] + rq.w, 0.f)};
        *(float4*)&nxt[(long)k * 1600 * 128 + rr * 128 + c0 + tc * 4] = o4;
    }
}

// ---------------- final: mean over k + relu, aa-attention, MLP ----------------
__global__ __launch_bounds__(256) void final_k(const float* __restrict__ cur,
    const float* __restrict__ waa, const float* __restrict__ baa,
    const float* __restrict__ w1, const float* __restrict__ b1,
    const float* __restrict__ w2, const float* __restrict__ b2,
    const float* __restrict__ w3, const float* __restrict__ b3,
    const float* __restrict__ w4, const float* __restrict__ b4, float* __restrict__ out)
{
    __shared__ float gl[50 * 129];
    __shared__ float sc[64];
    __shared__ float pl[128];
    __shared__ float h1l[64], h2l[32], h3l[16];
    __shared__ float wl[128];
    const int b = blockIdx.x, tid = threadIdx.x;
    for (int s = tid; s < 50 * 128; s += 256) {
        const int a = s >> 7, o = s & 127;
        const long r = (long)b * 50 + a;
        const float v = (cur[r * 128 + o] + cur[1600 * 128 + r * 128 + o] + cur[2 * 1600 * 128 + r * 128 + o]) * (1.f / 3.f);
        gl[a * 129 + o] = fmaxf(v, 0.f);
    }
    if (tid < 128) wl[tid] = waa[tid];
    __syncthreads();
    if (tid < 50) {
        float acc = baa[0];
        for (int f = 0; f < 128; ++f) acc = fmaf(gl[tid * 129 + f], wl[f], acc);
        sc[tid] = acc;
    }
    __syncthreads();
    if (tid < 64) {
        const float v = (tid < 50) ? sc[tid] : -1e30f;
        float m = v;
        for (int d = 32; d; d >>= 1) m = fmaxf(m, __shfl_xor(m, d));
        const float e = (tid < 50) ? expf(v - m) : 0.f;
        float ssum = e;
        for (int d = 32; d; d >>= 1) ssum += __shfl_xor(ssum, d);
        if (tid < 50) sc[tid] = e / ssum;
    }
    __syncthreads();
    if (tid < 128) {
        float acc = 0.f;
        for (int a = 0; a < 50; ++a) acc = fmaf(sc[a], gl[a * 129 + tid], acc);
        pl[tid] = acc;
    }
    __syncthreads();
    if (tid < 64) {
        float acc = b1[tid];
        for (int f = 0; f < 128; ++f) acc = fmaf(pl[f], w1[f * 64 + tid], acc);
        h1l[tid] = fmaxf(acc, 0.f);
    }
    __syncthreads();
    if (tid < 32) {
        float acc = b2[tid];
        for (int f = 0; f < 64; ++f) acc = fmaf(h1l[f], w2[f * 32 + tid], acc);
        h2l[tid] = fmaxf(acc, 0.f);
    }
    __syncthreads();
    if (tid < 16) {
        float acc = b3[tid];
        for (int f = 0; f < 32; ++f) acc = fmaf(h2l[f], w3[f * 16 + tid], acc);
        h3l[tid] = fmaxf(acc, 0.f);
    }
    __syncthreads();
    if (tid == 0) {
        float acc = b4[0];
        for (int f = 0; f < 16; ++f) acc = fmaf(h3l[f], w4[f], acc);
        out[b] = acc;
    }
}

extern "C" void kernel_launch(void* const* d_in, const int* in_sizes, int n_in,
                              void* d_out, int out_size, void* d_ws, size_t ws_size,
                              hipStream_t stream) {
    const float* x     = (const float*)d_in[0];
    const int*   eidx  = (const int*)d_in[1];
    const float* ea    = (const float*)d_in[2];
    const float* aaf   = (const float*)d_in[4];
    const float* we1   = (const float*)d_in[5];
    const float* be1   = (const float*)d_in[6];
    const float* root1 = (const float*)d_in[7];
    const float* bias1 = (const float*)d_in[8];
    const float* we2   = (const float*)d_in[9];
    const float* be2   = (const float*)d_in[10];
    const float* root2 = (const float*)d_in[11];
    const float* bias2 = (const float*)d_in[12];
    const float* waw   = (const float*)d_in[13];
    const float* wab   = (const float*)d_in[14];
    const float* initw = (const float*)d_in[15];
    const float* armaw = (const float*)d_in[16];
    const float* rootw = (const float*)d_in[17];
    const float* abias = (const float*)d_in[18];
    const float* waa   = (const float*)d_in[19];
    const float* baa   = (const float*)d_in[20];
    const float* w1    = (const float*)d_in[21];
    const float* b1    = (const float*)d_in[22];
    const float* w2    = (const float*)d_in[23];
    const float* b2    = (const float*)d_in[24];
    const float* w3    = (const float*)d_in[25];
    const float* b3    = (const float*)d_in[26];
    const float* w4    = (const float*)d_in[27];
    const float* b4    = (const float*)d_in[28];
    float* out = (float*)d_out;

    const int* src = eidx;
    const int* dst = eidx + N_EDGES;

    char* ws = (char*)d_ws;
    size_t off = 0;
    float* h1     = (float*)(ws + off); off += (size_t)N_NODES * 64 * 4;
    float* h2     = (float*)(ws + off); off += (size_t)N_NODES * 64 * 4;
    float* scores = (float*)(ws + off); off += (size_t)N_NODES * 4;
    float* attn   = (float*)(ws + off); off += (size_t)N_NODES * 4;
    float* xi     = (float*)(ws + off); off += (size_t)1600 * FIN * 4;
    float* RI     = (float*)(ws + off); off += (size_t)1600 * RICOLS * 4;
    float* curA   = (float*)(ws + off); off += (size_t)3 * 1600 * 128 * 4;
    float* curB   = (float*)(ws + off); off += (size_t)3 * 1600 * 128 * 4;
    ushort* wt1h  = (ushort*)(ws + off); off += (size_t)17 * 8 * 64 * 8 * 2;
    ushort* wt1l  = (ushort*)(ws + off); off += (size_t)17 * 8 * 64 * 8 * 2;
    ushort* wt2h  = (ushort*)(ws + off); off += (size_t)17 * 8 * 64 * 8 * 2;
    ushort* wt2l  = (ushort*)(ws + off); off += (size_t)17 * 8 * 64 * 8 * 2;

    // one-off weight transform to MFMA fragment layout (bf16 hi/lo)
    prep_w<<<34, 256, 0, stream>>>(we1, be1, wt1h, wt1l);
    prep_w<<<34, 256, 0, stream>>>(we2, be2, wt2h, wt2l);

    // conv1: h1 = x@root1 + bias1 + scatter(msg);  (relu deferred to consumers)
    root_gemm<0><<<N_NODES / 64, 256, 0, stream>>>(x, root1, bias1, h1);
    edge_conv_mfma<0><<<N_EDGES / TE, 256, 0, stream>>>(x, ea, src, dst, wt1h, wt1l, h1);
    // conv2: reads relu(h1) on load
    root_gemm<1><<<N_NODES / 64, 256, 0, stream>>>(h1, root2, bias2, h2);
    edge_conv_mfma<1><<<N_EDGES / TE, 256, 0, stream>>>(h1, ea, src, dst, wt2h, wt2l, h2);
    // atom attention -> residues -> xi (relu(h2) on load)
    scores_k<<<(N_NODES + 255) / 256, 256, 0, stream>>>(h2, waw, wab, scores);
    softmax_k<<<NB, 256, 0, stream>>>(scores, attn);
    amino_k<<<1600 / 4, 256, 0, stream>>>(h2, attn, aaf, xi);
    // ARMA
    ri_gemm<<<dim3(25, 42), 256, 0, stream>>>(xi, rootw, initw, abias, RI);
    arma_step<1><<<dim3(25, 2, 3), 256, 0, stream>>>(curB, RI, armaw, curA, 1);
    arma_step<0><<<dim3(25, 2, 3), 256, 0, stream>>>(curA, RI, armaw, curB, 2);
    arma_step<0><<<dim3(25, 2, 3), 256, 0, stream>>>(curB, RI, armaw, curA, 3);
    arma_step<0><<<dim3(25, 2, 3), 256, 0, stream>>>(curA, RI, armaw, curB, 4);
    arma_step<0><<<dim3(25, 2, 3), 256, 0, stream>>>(curB, RI, armaw, curA, 5);
    // readout + MLP
    final_k<<<NB, 256, 0, stream>>>(curA, waa, baa, w1, b1, w2, b2, w3, b3, w4, b4, out);
}

// Round 5
// 411.783 us; speedup vs baseline: 1.1938x; 1.1938x over previous
//
#include <hip/hip_runtime.h>

#define N_NODES 80000
#define N_EDGES 64000
#define NB      32
#define NG      2500
#define NA      50
#define EDIM    16
#define FIN     159      // H2(64) + AF(95)
#define HG      128
#define RICOLS  2688     // 21 blocks of 128: 18 root(t,k) + 3 init(k)

typedef __attribute__((ext_vector_type(8))) short bf16x8;
typedef __attribute__((ext_vector_type(4))) float f32x4;

__device__ inline ushort rne_bf16(float f) {
    union { float f; unsigned u; } v; v.f = f;
    const unsigned r = v.u + 0x7fffu + ((v.u >> 16) & 1u);
    return (ushort)(r >> 16);
}
__device__ inline float bf16_to_f32(ushort h) {
    union { unsigned u; float f; } v; v.u = ((unsigned)h) << 16;
    return v.f;
}

// ---------------- weight prep: w_e[16,64*64]+b_e[4096] -> bf16 hi/lo fragments ----------------
// Fragment order: Wt[((j*8 + n*2 + kq)*64 + lane)*8 + t] = bf16(W[j][i][o]),
//   o = n*16 + (lane&15), i = kq*32 + (lane>>4)*8 + t   (j==16 -> b_e)
__global__ __launch_bounds__(256) void prep_w(const float* __restrict__ we,
    const float* __restrict__ be, ushort* __restrict__ Whi, ushort* __restrict__ Wlo)
{
    const int idx = blockIdx.x * 256 + threadIdx.x;
    if (idx >= 17 * 8 * 64) return;
    const int l = idx & 63;
    const int slot = (idx >> 6) & 7;
    const int j = idx >> 9;
    const int n = slot >> 1, kq = slot & 1;
    const int o = n * 16 + (l & 15);
    const int i0 = kq * 32 + (l >> 4) * 8;
    ushort th[8], tl[8];
#pragma unroll
    for (int t = 0; t < 8; ++t) {
        const int i = i0 + t;
        const float f = (j < 16) ? we[j * 4096 + i * 64 + o] : be[i * 64 + o];
        const ushort hi = rne_bf16(f);
        th[t] = hi;
        tl[t] = rne_bf16(f - bf16_to_f32(hi));
    }
    *(uint4*)(Whi + (size_t)idx * 8) = *(const uint4*)th;
    *(uint4*)(Wlo + (size_t)idx * 8) = *(const uint4*)tl;
}

// ---------------- root GEMM: out[n,:] = relu?(in[n,:]) @ W(64x64) + bias ----------------
template<int RELU>
__global__ __launch_bounds__(256) void root_gemm(const float* __restrict__ in,
    const float* __restrict__ w, const float* __restrict__ bias, float* __restrict__ out)
{
    __shared__ float At[64 * 65];   // At[c*65 + r]
    __shared__ float Wl[64 * 64];   // [i*64 + o]
    __shared__ float bl[64];
    const int tid = threadIdx.x;
    const int r0 = blockIdx.x * 64;
    for (int s = tid; s < 4096; s += 256) {
        int r = s >> 6, c = s & 63;
        float v = in[(r0 + r) * 64 + c];
        if (RELU) v = fmaxf(v, 0.f);
        At[c * 65 + r] = v;
    }
    for (int s = tid; s < 4096; s += 256) Wl[s] = w[s];
    if (tid < 64) bl[tid] = bias[tid];
    __syncthreads();
    const int tr = tid >> 4, tc = tid & 15;
    float acc[4][4] = {};
#pragma unroll 8
    for (int i = 0; i < 64; ++i) {
        const float4 a4 = *(const float4*)&At[i * 65 + tr * 4];
        const float4 b4 = *(const float4*)&Wl[i * 64 + tc * 4];
        const float av[4] = {a4.x, a4.y, a4.z, a4.w};
        const float bv[4] = {b4.x, b4.y, b4.z, b4.w};
#pragma unroll
        for (int m = 0; m < 4; ++m)
#pragma unroll
            for (int n = 0; n < 4; ++n) acc[m][n] = fmaf(av[m], bv[n], acc[m][n]);
    }
    const float4 bq = *(const float4*)&bl[tc * 4];
#pragma unroll
    for (int m = 0; m < 4; ++m) {
        float4 o4 = {acc[m][0] + bq.x, acc[m][1] + bq.y, acc[m][2] + bq.z, acc[m][3] + bq.w};
        *(float4*)&out[(r0 + tr * 4 + m) * 64 + tc * 4] = o4;
    }
}

// ---------------- NNConv edge kernel, bf16x3 MFMA (R3 structure, TE=64) ----------------
// msg[e,o] = sum_j ea'[e,j] * (relu?(H[src_e,:]) @ Wj)[o]
// Wave wv owns edges wv*16..wv*16+15, all 64 outputs. B streamed per-wave from L2.
#define TE 64
template<int RELU>
__global__ __launch_bounds__(256) void edge_conv_mfma(const float* __restrict__ h,
    const float* __restrict__ ea, const int* __restrict__ src, const int* __restrict__ dst,
    const ushort* __restrict__ Whi, const ushort* __restrict__ Wlo, float* __restrict__ agg)
{
    __shared__ ushort Hh[TE * 64];      // bf16 hi, XOR-swizzled rows
    __shared__ ushort Hl[TE * 64];      // bf16 lo
    __shared__ float  MS[TE * 64];      // msg stash for coalesced scatter
    __shared__ float  EAt[17 * 68];     // [j][edge]
    __shared__ int    SR[TE], DS[TE];
    const int tid = threadIdx.x;
    const int e0 = blockIdx.x * TE;

    if (tid < TE) SR[tid] = src[e0 + tid];
    else if (tid < 2 * TE) DS[tid - TE] = dst[e0 + tid - TE];
    __syncthreads();

    // gather H rows -> bf16 hi/lo -> swizzled LDS (byte ^= (row&7)<<4)
    for (int q = tid; q < TE * 16; q += 256) {
        const int le = q >> 4, iq = q & 15;
        const float4 v = *(const float4*)(h + (long)SR[le] * 64 + iq * 4);
        const float fv[4] = {v.x, v.y, v.z, v.w};
        ushort bh[4], bl[4];
#pragma unroll
        for (int t = 0; t < 4; ++t) {
            const float f = RELU ? fmaxf(fv[t], 0.f) : fv[t];
            bh[t] = rne_bf16(f);
            bl[t] = rne_bf16(f - bf16_to_f32(bh[t]));
        }
        const int byte = le * 128 + ((iq * 8) ^ ((le & 7) << 4));
        *(ushort4*)((char*)Hh + byte) = *(const ushort4*)bh;
        *(ushort4*)((char*)Hl + byte) = *(const ushort4*)bl;
    }
    // edge attrs transposed [j][e] (+ 1.0 row for bias)
    for (int s = tid; s < TE * 16; s += 256) {
        const int le = s >> 4, j = s & 15;
        EAt[j * 68 + le] = ea[(long)(e0 + le) * 16 + j];
    }
    if (tid < TE) EAt[16 * 68 + tid] = 1.0f;
    __syncthreads();

    const int wv = tid >> 6, l = tid & 63;

    // A fragments to registers once; reused across all 17 j
    bf16x8 ah[2], al[2];
#pragma unroll
    for (int kq = 0; kq < 2; ++kq) {
        const int row = wv * 16 + (l & 15);
        const int byte = row * 128 + ((kq * 64 + (l >> 4) * 16) ^ ((row & 7) << 4));
        ah[kq] = *(const bf16x8*)((const char*)Hh + byte);
        al[kq] = *(const bf16x8*)((const char*)Hl + byte);
    }

    f32x4 msg[4];
#pragma unroll
    for (int n = 0; n < 4; ++n) msg[n] = (f32x4)0.f;

#pragma unroll 1
    for (int j = 0; j < 17; ++j) {
        bf16x8 bh[4][2], bl[4][2];
#pragma unroll
        for (int n = 0; n < 4; ++n)
#pragma unroll
            for (int kq = 0; kq < 2; ++kq) {
                const size_t fo = ((size_t)(j * 8 + n * 2 + kq) * 64 + l) * 8;
                bh[n][kq] = *(const bf16x8*)(Whi + fo);
                bl[n][kq] = *(const bf16x8*)(Wlo + fo);
            }
        const f32x4 eam = *(const f32x4*)&EAt[j * 68 + wv * 16 + (l >> 4) * 4];
#pragma unroll
        for (int n = 0; n < 4; ++n) {
            f32x4 t = __builtin_amdgcn_mfma_f32_16x16x32_bf16(ah[0], bh[n][0], (f32x4)0.f, 0, 0, 0);
            t = __builtin_amdgcn_mfma_f32_16x16x32_bf16(ah[1], bh[n][1], t, 0, 0, 0);
            t = __builtin_amdgcn_mfma_f32_16x16x32_bf16(ah[0], bl[n][0], t, 0, 0, 0);
            t = __builtin_amdgcn_mfma_f32_16x16x32_bf16(ah[1], bl[n][1], t, 0, 0, 0);
            t = __builtin_amdgcn_mfma_f32_16x16x32_bf16(al[0], bh[n][0], t, 0, 0, 0);
            t = __builtin_amdgcn_mfma_f32_16x16x32_bf16(al[1], bh[n][1], t, 0, 0, 0);
            msg[n] += eam * t;
        }
    }

    // stash msg in LDS, then coalesced atomic scatter.
    // C/D layout: col=l&15 within n-tile, row=(l>>4)*4+r
#pragma unroll
    for (int n = 0; n < 4; ++n)
#pragma unroll
        for (int r = 0; r < 4; ++r)
            MS[(wv * 16 + (l >> 4) * 4 + r) * 64 + n * 16 + (l & 15)] = msg[n][r];
    __syncthreads();
    for (int s = tid; s < TE * 64; s += 256) {
        const int le = s >> 6, o = s & 63;
        atomicAdd(&agg[(long)DS[le] * 64 + o], MS[s]);
    }
}

// ---------------- atom attention scores (relu on load) ----------------
__global__ __launch_bounds__(256) void scores_k(const float* __restrict__ h2,
    const float* __restrict__ w, const float* __restrict__ b, float* __restrict__ sc)
{
    __shared__ float wl[64];
    if (threadIdx.x < 64) wl[threadIdx.x] = w[threadIdx.x];
    __syncthreads();
    const int n = blockIdx.x * 256 + threadIdx.x;
    if (n < N_NODES) {
        float acc = b[0];
        const float4* hp = (const float4*)(h2 + (long)n * 64);
#pragma unroll
        for (int q = 0; q < 16; ++q) {
            const float4 v = hp[q];
            acc = fmaf(fmaxf(v.x, 0.f), wl[q * 4 + 0], acc); acc = fmaf(fmaxf(v.y, 0.f), wl[q * 4 + 1], acc);
            acc = fmaf(fmaxf(v.z, 0.f), wl[q * 4 + 2], acc); acc = fmaf(fmaxf(v.w, 0.f), wl[q * 4 + 3], acc);
        }
        sc[n] = acc;
    }
}

// ---------------- per-graph softmax over atoms ----------------
__global__ __launch_bounds__(256) void softmax_k(const float* __restrict__ sc, float* __restrict__ attn)
{
    __shared__ float red[256];
    const int g = blockIdx.x, tid = threadIdx.x;
    const float* s = sc + (long)g * NG;
    float m = -1e30f;
    for (int a = tid; a < NG; a += 256) m = fmaxf(m, s[a]);
    red[tid] = m; __syncthreads();
    for (int st = 128; st; st >>= 1) { if (tid < st) red[tid] = fmaxf(red[tid], red[tid + st]); __syncthreads(); }
    const float mx = red[0]; __syncthreads();
    float sum = 0.f;
    for (int a = tid; a < NG; a += 256) sum += expf(s[a] - mx);
    red[tid] = sum; __syncthreads();
    for (int st = 128; st; st >>= 1) { if (tid < st) red[tid] += red[tid + st]; __syncthreads(); }
    const float inv = 1.0f / red[0];
    for (int a = tid; a < NG; a += 256) attn[(long)g * NG + a] = expf(s[a] - mx) * inv;
}

// ---------------- residue pooling + xi concat (relu on load) ----------------
__global__ __launch_bounds__(256) void amino_k(const float* __restrict__ h2,
    const float* __restrict__ attn, const float* __restrict__ aa, float* __restrict__ xi)
{
    const int tid = threadIdx.x;
    const int r = blockIdx.x * 4 + (tid >> 6);   // global residue 0..1599
    const int o = tid & 63;
    const int g = r / NA, ar = r % NA;
    const long base = (long)g * NG + ar * 50;
    float acc = 0.f;
#pragma unroll 10
    for (int a = 0; a < 50; ++a) acc = fmaf(attn[base + a], fmaxf(h2[(base + a) * 64 + o], 0.f), acc);
    xi[(long)r * FIN + o] = acc;
    for (int s = tid; s < 4 * 95; s += 256) {
        const int lr = s / 95, f = s % 95;
        const int rr = blockIdx.x * 4 + lr;
        xi[(long)rr * FIN + 64 + f] = aa[(long)rr * 95 + f];
    }
}

// ---------------- RI GEMM: [1600,159] @ [159,2688] (+bias on root cols) ----------------
__global__ __launch_bounds__(256) void ri_gemm(const float* __restrict__ xi,
    const float* __restrict__ rootw, const float* __restrict__ initw,
    const float* __restrict__ abias, float* __restrict__ RI)
{
    __shared__ float At[32 * 65];   // [kk*65 + r]
    __shared__ float Bl[32 * 64];   // [kk*64 + cc]
    const int tid = threadIdx.x;
    const int r0 = blockIdx.x * 64, c0 = blockIdx.y * 64;
    const int blk = c0 >> 7;             // 0..20
    const int gb = c0 & 127;             // 0 or 64
    const float* bsrc = (blk < 18) ? (rootw + (long)blk * FIN * 128) : (initw + (long)(blk - 18) * FIN * 128);
    const int tr = tid >> 4, tc = tid & 15;
    float acc[4][4] = {};
    for (int f0 = 0; f0 < FIN; f0 += 32) {
        __syncthreads();
        for (int s = tid; s < 64 * 32; s += 256) {
            const int r = s >> 5, kk = s & 31; const int f = f0 + kk;
            At[kk * 65 + r] = (f < FIN) ? xi[(long)(r0 + r) * FIN + f] : 0.f;
        }
        for (int s = tid; s < 32 * 64; s += 256) {
            const int kk = s >> 6, cc = s & 63; const int f = f0 + kk;
            Bl[s] = (f < FIN) ? bsrc[(long)f * 128 + gb + cc] : 0.f;
        }
        __syncthreads();
#pragma unroll 8
        for (int kk = 0; kk < 32; ++kk) {
            const float4 a4 = *(const float4*)&At[kk * 65 + tr * 4];
            const float4 b4 = *(const float4*)&Bl[kk * 64 + tc * 4];
            const float av[4] = {a4.x, a4.y, a4.z, a4.w};
            const float bv[4] = {b4.x, b4.y, b4.z, b4.w};
#pragma unroll
            for (int m = 0; m < 4; ++m)
#pragma unroll
                for (int n = 0; n < 4; ++n) acc[m][n] = fmaf(av[m], bv[n], acc[m][n]);
        }
    }
    float4 bq = {0.f, 0.f, 0.f, 0.f};
    if (blk < 18) bq = *(const float4*)&abias[c0 + tc * 4];
#pragma unroll
    for (int m = 0; m < 4; ++m) {
        float4 o4 = {acc[m][0] + bq.x, acc[m][1] + bq.y, acc[m][2] + bq.z, acc[m][3] + bq.w};
        *(float4*)&RI[(long)(r0 + tr * 4 + m) * RICOLS + c0 + tc * 4] = o4;
    }
}

// ---------------- ARMA step t: nxt = relu(shift(cur) @ W[t-1,k] + RI_root[t,k]) ----------------
// INIT=1 (t==1): cur is synthesized on the fly from RI (t=0 output), no arma0 pass.
template<int INIT>
__global__ __launch_bounds__(256) void arma_step(const float* __restrict__ cur,
    const float* __restrict__ RI, const float* __restrict__ armaw, float* __restrict__ nxt, int t)
{
    __shared__ float Al[64 * 64];   // [r*64 + ff] (per 64-wide f chunk)
    __shared__ float Bl[64 * 64];   // [ff*64 + cc]
    const int tid = threadIdx.x;
    const int r0 = blockIdx.x * 64, c0 = blockIdx.y * 64, k = blockIdx.z;
    const float* W = armaw + (long)((t - 1) * 3 + k) * 128 * 128;
    const int tr = tid >> 4, tc = tid & 15;
    float acc[4][4] = {};
    for (int f0 = 0; f0 < 128; f0 += 64) {
        __syncthreads();
        for (int s = tid; s < 4096; s += 256) {
            const int r = s >> 6, ff = s & 63;
            const int rr = r0 + r; const int a = rr % NA;
            float v = 0.f;
            if (INIT) {
                if (a >= 2) {
                    v = RI[(long)(rr - 1) * RICOLS + k * 128 + f0 + ff];
                    if (a >= 3) v += RI[(long)(rr - 2) * RICOLS + (18 + k) * 128 + f0 + ff];
                    v = fmaxf(v, 0.f);
                }
            } else {
                if (a >= 2) v = cur[(long)k * 1600 * 128 + (rr - 1) * 128 + f0 + ff];
            }
            Al[s] = v;
        }
        for (int s = tid; s < 4096; s += 256) {
            const int ff = s >> 6, cc = s & 63;
            Bl[s] = W[(long)(f0 + ff) * 128 + c0 + cc];
        }
        __syncthreads();
#pragma unroll 8
        for (int ff = 0; ff < 64; ++ff) {
            const float4 b4 = *(const float4*)&Bl[ff * 64 + tc * 4];
            const float bv[4] = {b4.x, b4.y, b4.z, b4.w};
#pragma unroll
            for (int m = 0; m < 4; ++m) {
                const float av = Al[(tr * 4 + m) * 64 + ff];
#pragma unroll
                for (int n = 0; n < 4; ++n) acc[m][n] = fmaf(av, bv[n], acc[m][n]);
            }
        }
    }
#pragma unroll
    for (int m = 0; m < 4; ++m) {
        const int rr = r0 + tr * 4 + m;
        const float4 rq = *(const float4*)&RI[(long)rr * RICOLS + (t * 3 + k) * 128 + c0 + tc * 4];
        float4 o4 = {fmaxf(acc[m][0] + rq.x, 0.f), fmaxf(acc[m][1] + rq.y, 0.f),
                     fmaxf(acc[m][2] + rq.z, 0.f), fmaxf(acc[m][3] + rq.w, 0.f)};
        *(float4*)&nxt[(long)k * 1600 * 128 + rr * 128 + c0 + tc * 4] = o4;
    }
}

// ---------------- final: mean over k + relu, aa-attention, MLP ----------------
__global__ __launch_bounds__(256) void final_k(const float* __restrict__ cur,
    const float* __restrict__ waa, const float* __restrict__ baa,
    const float* __restrict__ w1, const float* __restrict__ b1,
    const float* __restrict__ w2, const float* __restrict__ b2,
    const float* __restrict__ w3, const float* __restrict__ b3,
    const float* __restrict__ w4, const float* __restrict__ b4, float* __restrict__ out)
{
    __shared__ float gl[50 * 129];
    __shared__ float sc[64];
    __shared__ float pl[128];
    __shared__ float h1l[64], h2l[32], h3l[16];
    __shared__ float wl[128];
    const int b = blockIdx.x, tid = threadIdx.x;
    for (int s = tid; s < 50 * 128; s += 256) {
        const int a = s >> 7, o = s & 127;
        const long r = (long)b * 50 + a;
        const float v = (cur[r * 128 + o] + cur[1600 * 128 + r * 128 + o] + cur[2 * 1600 * 128 + r * 128 + o]) * (1.f / 3.f);
        gl[a * 129 + o] = fmaxf(v, 0.f);
    }
    if (tid < 128) wl[tid] = waa[tid];
    __syncthreads();
    if (tid < 50) {
        float acc = baa[0];
        for (int f = 0; f < 128; ++f) acc = fmaf(gl[tid * 129 + f], wl[f], acc);
        sc[tid] = acc;
    }
    __syncthreads();
    if (tid < 64) {
        const float v = (tid < 50) ? sc[tid] : -1e30f;
        float m = v;
        for (int d = 32; d; d >>= 1) m = fmaxf(m, __shfl_xor(m, d));
        const float e = (tid < 50) ? expf(v - m) : 0.f;
        float ssum = e;
        for (int d = 32; d; d >>= 1) ssum += __shfl_xor(ssum, d);
        if (tid < 50) sc[tid] = e / ssum;
    }
    __syncthreads();
    if (tid < 128) {
        float acc = 0.f;
        for (int a = 0; a < 50; ++a) acc = fmaf(sc[a], gl[a * 129 + tid], acc);
        pl[tid] = acc;
    }
    __syncthreads();
    if (tid < 64) {
        float acc = b1[tid];
        for (int f = 0; f < 128; ++f) acc = fmaf(pl[f], w1[f * 64 + tid], acc);
        h1l[tid] = fmaxf(acc, 0.f);
    }
    __syncthreads();
    if (tid < 32) {
        float acc = b2[tid];
        for (int f = 0; f < 64; ++f) acc = fmaf(h1l[f], w2[f * 32 + tid], acc);
        h2l[tid] = fmaxf(acc, 0.f);
    }
    __syncthreads();
    if (tid < 16) {
        float acc = b3[tid];
        for (int f = 0; f < 32; ++f) acc = fmaf(h2l[f], w3[f * 16 + tid], acc);
        h3l[tid] = fmaxf(acc, 0.f);
    }
    __syncthreads();
    if (tid == 0) {
        float acc = b4[0];
        for (int f = 0; f < 16; ++f) acc = fmaf(h3l[f], w4[f], acc);
        out[b] = acc;
    }
}

extern "C" void kernel_launch(void* const* d_in, const int* in_sizes, int n_in,
                              void* d_out, int out_size, void* d_ws, size_t ws_size,
                              hipStream_t stream) {
    const float* x     = (const float*)d_in[0];
    const int*   eidx  = (const int*)d_in[1];
    const float* ea    = (const float*)d_in[2];
    const float* aaf   = (const float*)d_in[4];
    const float* we1   = (const float*)d_in[5];
    const float* be1   = (const float*)d_in[6];
    const float* root1 = (const float*)d_in[7];
    const float* bias1 = (const float*)d_in[8];
    const float* we2   = (const float*)d_in[9];
    const float* be2   = (const float*)d_in[10];
    const float* root2 = (const float*)d_in[11];
    const float* bias2 = (const float*)d_in[12];
    const float* waw   = (const float*)d_in[13];
    const float* wab   = (const float*)d_in[14];
    const float* initw = (const float*)d_in[15];
    const float* armaw = (const float*)d_in[16];
    const float* rootw = (const float*)d_in[17];
    const float* abias = (const float*)d_in[18];
    const float* waa   = (const float*)d_in[19];
    const float* baa   = (const float*)d_in[20];
    const float* w1    = (const float*)d_in[21];
    const float* b1    = (const float*)d_in[22];
    const float* w2    = (const float*)d_in[23];
    const float* b2    = (const float*)d_in[24];
    const float* w3    = (const float*)d_in[25];
    const float* b3    = (const float*)d_in[26];
    const float* w4    = (const float*)d_in[27];
    const float* b4    = (const float*)d_in[28];
    float* out = (float*)d_out;

    const int* src = eidx;
    const int* dst = eidx + N_EDGES;

    char* ws = (char*)d_ws;
    size_t off = 0;
    float* h1     = (float*)(ws + off); off += (size_t)N_NODES * 64 * 4;
    float* h2     = (float*)(ws + off); off += (size_t)N_NODES * 64 * 4;
    float* scores = (float*)(ws + off); off += (size_t)N_NODES * 4;
    float* attn   = (float*)(ws + off); off += (size_t)N_NODES * 4;
    float* xi     = (float*)(ws + off); off += (size_t)1600 * FIN * 4;
    float* RI     = (float*)(ws + off); off += (size_t)1600 * RICOLS * 4;
    float* curA   = (float*)(ws + off); off += (size_t)3 * 1600 * 128 * 4;
    float* curB   = (float*)(ws + off); off += (size_t)3 * 1600 * 128 * 4;
    ushort* wt1h  = (ushort*)(ws + off); off += (size_t)17 * 8 * 64 * 8 * 2;
    ushort* wt1l  = (ushort*)(ws + off); off += (size_t)17 * 8 * 64 * 8 * 2;
    ushort* wt2h  = (ushort*)(ws + off); off += (size_t)17 * 8 * 64 * 8 * 2;
    ushort* wt2l  = (ushort*)(ws + off); off += (size_t)17 * 8 * 64 * 8 * 2;

    // one-off weight transform to MFMA fragment layout (bf16 hi/lo)
    prep_w<<<34, 256, 0, stream>>>(we1, be1, wt1h, wt1l);
    prep_w<<<34, 256, 0, stream>>>(we2, be2, wt2h, wt2l);

    // conv1: h1 = x@root1 + bias1 + scatter(msg);  (relu deferred to consumers)
    root_gemm<0><<<N_NODES / 64, 256, 0, stream>>>(x, root1, bias1, h1);
    edge_conv_mfma<0><<<N_EDGES / TE, 256, 0, stream>>>(x, ea, src, dst, wt1h, wt1l, h1);
    // conv2: reads relu(h1) on load
    root_gemm<1><<<N_NODES / 64, 256, 0, stream>>>(h1, root2, bias2, h2);
    edge_conv_mfma<1><<<N_EDGES / TE, 256, 0, stream>>>(h1, ea, src, dst, wt2h, wt2l, h2);
    // atom attention -> residues -> xi (relu(h2) on load)
    scores_k<<<(N_NODES + 255) / 256, 256, 0, stream>>>(h2, waw, wab, scores);
    softmax_k<<<NB, 256, 0, stream>>>(scores, attn);
    amino_k<<<1600 / 4, 256, 0, stream>>>(h2, attn, aaf, xi);
    // ARMA
    ri_gemm<<<dim3(25, 42), 256, 0, stream>>>(xi, rootw, initw, abias, RI);
    arma_step<1><<<dim3(25, 2, 3), 256, 0, stream>>>(curB, RI, armaw, curA, 1);
    arma_step<0><<<dim3(25, 2, 3), 256, 0, stream>>>(curA, RI, armaw, curB, 2);
    arma_step<0><<<dim3(25, 2, 3), 256, 0, stream>>>(curB, RI, armaw, curA, 3);
    arma_step<0><<<dim3(25, 2, 3), 256, 0, stream>>>(curA, RI, armaw, curB, 4);
    arma_step<0><<<dim3(25, 2, 3), 256, 0, stream>>>(curB, RI, armaw, curA, 5);
    // readout + MLP
    final_k<<<NB, 256, 0, stream>>>(curA, waa, baa, w1, b1, w2, b2, w3, b3, w4, b4, out);
}

// Round 6
// 373.181 us; speedup vs baseline: 1.3173x; 1.1034x over previous
//
#include <hip/hip_runtime.h>

#define N_NODES 80000
#define N_EDGES 64000
#define NB      32
#define NG      2500
#define NA      50
#define EDIM    16
#define FIN     159      // H2(64) + AF(95)
#define HG      128
#define RICOLS  2688     // 21 blocks of 128: 18 root(t,k) + 3 init(k)

typedef __attribute__((ext_vector_type(8))) short bf16x8;
typedef __attribute__((ext_vector_type(4))) float f32x4;

__device__ inline ushort rne_bf16(float f) {
    union { float f; unsigned u; } v; v.f = f;
    const unsigned r = v.u + 0x7fffu + ((v.u >> 16) & 1u);
    return (ushort)(r >> 16);
}
__device__ inline float bf16_to_f32(ushort h) {
    union { unsigned u; float f; } v; v.u = ((unsigned)h) << 16;
    return v.f;
}
__device__ __forceinline__ void gl_lds16(const void* gsrc, void* ldst) {
    __builtin_amdgcn_global_load_lds(
        (const __attribute__((address_space(1))) unsigned int*)gsrc,
        (__attribute__((address_space(3))) unsigned int*)ldst, 16, 0, 0);
}

// ---------------- weight prep (both convs): -> bf16 hi/lo fragments ----------------
// Wt[((j*8 + n*2 + kq)*64 + lane)*8 + t] = bf16(W[j][i][o]), o=n*16+(l&15), i=kq*32+(l>>4)*8+t (j==16 -> b_e)
__global__ __launch_bounds__(256) void prep_w2(const float* __restrict__ we1, const float* __restrict__ be1,
    const float* __restrict__ we2, const float* __restrict__ be2,
    ushort* __restrict__ w1h, ushort* __restrict__ w1l, ushort* __restrict__ w2h, ushort* __restrict__ w2l)
{
    int idx = blockIdx.x * 256 + threadIdx.x;
    const int half = (idx >= 17 * 8 * 64) ? 1 : 0;
    if (half) idx -= 17 * 8 * 64;
    if (idx >= 17 * 8 * 64) return;
    const float* we = half ? we2 : we1;
    const float* be = half ? be2 : be1;
    ushort* Wh = half ? w2h : w1h;
    ushort* Wlo = half ? w2l : w1l;
    const int l = idx & 63;
    const int slot = (idx >> 6) & 7;
    const int j = idx >> 9;
    const int n = slot >> 1, kq = slot & 1;
    const int o = n * 16 + (l & 15);
    const int i0 = kq * 32 + (l >> 4) * 8;
    ushort th[8], tl[8];
#pragma unroll
    for (int t = 0; t < 8; ++t) {
        const int i = i0 + t;
        const float f = (j < 16) ? we[j * 4096 + i * 64 + o] : be[i * 64 + o];
        const ushort hi = rne_bf16(f);
        th[t] = hi;
        tl[t] = rne_bf16(f - bf16_to_f32(hi));
    }
    *(uint4*)(Wh + (size_t)idx * 8) = *(const uint4*)th;
    *(uint4*)(Wlo + (size_t)idx * 8) = *(const uint4*)tl;
}

// ---------------- root GEMM: out[n,:] = relu?(in[n,:]) @ W(64x64) + bias ----------------
template<int RELU>
__global__ __launch_bounds__(256) void root_gemm(const float* __restrict__ in,
    const float* __restrict__ w, const float* __restrict__ bias, float* __restrict__ out)
{
    __shared__ float At[64 * 65];
    __shared__ float Wl[64 * 64];
    __shared__ float bl[64];
    const int tid = threadIdx.x;
    const int r0 = blockIdx.x * 64;
    for (int s = tid; s < 4096; s += 256) {
        int r = s >> 6, c = s & 63;
        float v = in[(r0 + r) * 64 + c];
        if (RELU) v = fmaxf(v, 0.f);
        At[c * 65 + r] = v;
    }
    for (int s = tid; s < 4096; s += 256) Wl[s] = w[s];
    if (tid < 64) bl[tid] = bias[tid];
    __syncthreads();
    const int tr = tid >> 4, tc = tid & 15;
    float acc[4][4] = {};
#pragma unroll 8
    for (int i = 0; i < 64; ++i) {
        const float4 a4 = *(const float4*)&At[i * 65 + tr * 4];
        const float4 b4 = *(const float4*)&Wl[i * 64 + tc * 4];
        const float av[4] = {a4.x, a4.y, a4.z, a4.w};
        const float bv[4] = {b4.x, b4.y, b4.z, b4.w};
#pragma unroll
        for (int m = 0; m < 4; ++m)
#pragma unroll
            for (int n = 0; n < 4; ++n) acc[m][n] = fmaf(av[m], bv[n], acc[m][n]);
    }
    const float4 bq = *(const float4*)&bl[tc * 4];
#pragma unroll
    for (int m = 0; m < 4; ++m) {
        float4 o4 = {acc[m][0] + bq.x, acc[m][1] + bq.y, acc[m][2] + bq.z, acc[m][3] + bq.w};
        *(float4*)&out[(r0 + tr * 4 + m) * 64 + tc * 4] = o4;
    }
}

// ---------------- NNConv edge kernel: bf16x3 MFMA, B in LDS via global_load_lds dbuf ----------------
#define TE 128
template<int RELU>
__global__ __launch_bounds__(256) void edge_conv_mfma(const float* __restrict__ h,
    const float* __restrict__ ea, const int* __restrict__ src, const int* __restrict__ dst,
    const ushort* __restrict__ Whi, const ushort* __restrict__ Wlo, float* __restrict__ agg)
{
    __shared__ ushort Bst[2][8192];     // per buf 16KB: hi slots [0,4096) lo slots [4096,8192) (ushort units)
    __shared__ float  EAt[17 * 132];    // [j][edge]
    const int tid = threadIdx.x;
    const int e0 = blockIdx.x * TE;
    const int wv = tid >> 6, l = tid & 63;

    // async prefetch B(j=0): each wave 4 chunks of 1KB (chunk c: c<8 hi slot c, else lo slot c-8)
#pragma unroll
    for (int i = 0; i < 4; ++i) {
        const int c = wv * 4 + i;
        const ushort* gs = (c < 8) ? (Whi + ((size_t)c * 64 + l) * 8)
                                   : (Wlo + ((size_t)(c - 8) * 64 + l) * 8);
        gl_lds16(gs, (char*)(&Bst[0][0]) + c * 1024);
    }
    // edge attrs transposed [j][e] (+1.0 bias row)
    for (int s = tid; s < TE * 16; s += 256) {
        const int le = s >> 4, j = s & 15;
        EAt[j * 132 + le] = ea[(size_t)(e0 + le) * 16 + j];
    }
    if (tid < TE) EAt[16 * 132 + tid] = 1.0f;

    // A fragments per-lane straight from global (hi/lo)
    bf16x8 ah[2][2], al[2][2];
#pragma unroll
    for (int m = 0; m < 2; ++m) {
        const int erow = wv * 32 + m * 16 + (l & 15);
        const int nd = src[e0 + erow];
        const float4* hp = (const float4*)(h + (size_t)nd * 64);
#pragma unroll
        for (int kq = 0; kq < 2; ++kq) {
            const int q0 = kq * 8 + (l >> 4) * 2;
            const float4 v0 = hp[q0], v1 = hp[q0 + 1];
            const float fv[8] = {v0.x, v0.y, v0.z, v0.w, v1.x, v1.y, v1.z, v1.w};
            ushort th[8], tl[8];
#pragma unroll
            for (int t = 0; t < 8; ++t) {
                const float f = RELU ? fmaxf(fv[t], 0.f) : fv[t];
                th[t] = rne_bf16(f);
                tl[t] = rne_bf16(f - bf16_to_f32(th[t]));
            }
            ah[m][kq] = *(const bf16x8*)th;
            al[m][kq] = *(const bf16x8*)tl;
        }
    }
    __syncthreads();   // drains B(0) + EA

    f32x4 msg[2][4];
#pragma unroll
    for (int m = 0; m < 2; ++m)
#pragma unroll
        for (int n = 0; n < 4; ++n) msg[m][n] = (f32x4)0.f;

#pragma unroll 1
    for (int j = 0; j < 17; ++j) {
        const int cur = j & 1;
        if (j < 16) {
#pragma unroll
            for (int i = 0; i < 4; ++i) {
                const int c = wv * 4 + i;
                const ushort* gs = (c < 8) ? (Whi + ((size_t)((j + 1) * 8 + c) * 64 + l) * 8)
                                           : (Wlo + ((size_t)((j + 1) * 8 + (c - 8)) * 64 + l) * 8);
                gl_lds16(gs, (char*)(&Bst[cur ^ 1][0]) + c * 1024);
            }
        }
        f32x4 eam[2];
        eam[0] = *(const f32x4*)&EAt[j * 132 + wv * 32 + (l >> 4) * 4];
        eam[1] = *(const f32x4*)&EAt[j * 132 + wv * 32 + 16 + (l >> 4) * 4];
#pragma unroll
        for (int n = 0; n < 4; ++n) {
            const char* bb = (const char*)(&Bst[cur][0]);
            const bf16x8 bh0 = *(const bf16x8*)(bb + ((n * 2 + 0) * 64 + l) * 16);
            const bf16x8 bh1 = *(const bf16x8*)(bb + ((n * 2 + 1) * 64 + l) * 16);
            const bf16x8 bl0 = *(const bf16x8*)(bb + 8192 + ((n * 2 + 0) * 64 + l) * 16);
            const bf16x8 bl1 = *(const bf16x8*)(bb + 8192 + ((n * 2 + 1) * 64 + l) * 16);
#pragma unroll
            for (int m = 0; m < 2; ++m) {
                f32x4 t = __builtin_amdgcn_mfma_f32_16x16x32_bf16(ah[m][0], bh0, (f32x4)0.f, 0, 0, 0);
                t = __builtin_amdgcn_mfma_f32_16x16x32_bf16(ah[m][1], bh1, t, 0, 0, 0);
                t = __builtin_amdgcn_mfma_f32_16x16x32_bf16(ah[m][0], bl0, t, 0, 0, 0);
                t = __builtin_amdgcn_mfma_f32_16x16x32_bf16(ah[m][1], bl1, t, 0, 0, 0);
                t = __builtin_amdgcn_mfma_f32_16x16x32_bf16(al[m][0], bh0, t, 0, 0, 0);
                t = __builtin_amdgcn_mfma_f32_16x16x32_bf16(al[m][1], bh1, t, 0, 0, 0);
                msg[m][n] += eam[m] * t;
            }
        }
        __syncthreads();
    }

    // direct atomic scatter (R3-verified clean-write pattern): col=n*16+(l&15), row=(l>>4)*4+r
#pragma unroll
    for (int m = 0; m < 2; ++m)
#pragma unroll
        for (int r = 0; r < 4; ++r) {
            const int erow = wv * 32 + m * 16 + (l >> 4) * 4 + r;
            const size_t d = (size_t)dst[e0 + erow] * 64;
#pragma unroll
            for (int n = 0; n < 4; ++n)
                atomicAdd(&agg[d + n * 16 + (l & 15)], msg[m][n][r]);
        }
}

// ---------------- fused atom-attention pooling: scores + softmax + residue pool + concat ----------------
__global__ __launch_bounds__(256) void pool_k(const float* __restrict__ h2,
    const float* __restrict__ waw, const float* __restrict__ wab,
    const float* __restrict__ aaf, float* __restrict__ xi)
{
    __shared__ float wl[64];
    __shared__ float sc[NG];
    __shared__ float red[256];
    const int g = blockIdx.x, tid = threadIdx.x;
    if (tid < 64) wl[tid] = waw[tid];
    __syncthreads();
    const size_t gb = (size_t)g * NG;
    const float bia = wab[0];
    for (int a = tid; a < NG; a += 256) {
        const float4* hp = (const float4*)(h2 + (gb + a) * 64);
        float acc = bia;
#pragma unroll
        for (int q = 0; q < 16; ++q) {
            const float4 v = hp[q];
            acc = fmaf(fmaxf(v.x, 0.f), wl[q * 4 + 0], acc);
            acc = fmaf(fmaxf(v.y, 0.f), wl[q * 4 + 1], acc);
            acc = fmaf(fmaxf(v.z, 0.f), wl[q * 4 + 2], acc);
            acc = fmaf(fmaxf(v.w, 0.f), wl[q * 4 + 3], acc);
        }
        sc[a] = acc;
    }
    __syncthreads();
    float m = -1e30f;
    for (int a = tid; a < NG; a += 256) m = fmaxf(m, sc[a]);
    red[tid] = m; __syncthreads();
    for (int st = 128; st; st >>= 1) { if (tid < st) red[tid] = fmaxf(red[tid], red[tid + st]); __syncthreads(); }
    const float mx = red[0]; __syncthreads();
    float s = 0.f;
    for (int a = tid; a < NG; a += 256) { const float e = expf(sc[a] - mx); sc[a] = e; s += e; }
    red[tid] = s; __syncthreads();
    for (int st = 128; st; st >>= 1) { if (tid < st) red[tid] += red[tid + st]; __syncthreads(); }
    const float inv = 1.0f / red[0];
    __syncthreads();
    for (int idx = tid; idx < NA * 64; idx += 256) {
        const int res = idx >> 6, o = idx & 63;
        const size_t rb = gb + (size_t)res * 50;
        float acc = 0.f;
#pragma unroll 10
        for (int i = 0; i < 50; ++i)
            acc = fmaf(sc[res * 50 + i], fmaxf(h2[(rb + i) * 64 + o], 0.f), acc);
        xi[((size_t)g * NA + res) * FIN + o] = acc * inv;
    }
    for (int s2 = tid; s2 < NA * 95; s2 += 256) {
        const int lr = s2 / 95, f = s2 % 95;
        xi[((size_t)g * NA + lr) * FIN + 64 + f] = aaf[((size_t)g * NA + lr) * 95 + f];
    }
}

// ---------------- RI GEMM: [1600,159] @ [159,2688] (+bias on root cols) ----------------
__global__ __launch_bounds__(256) void ri_gemm(const float* __restrict__ xi,
    const float* __restrict__ rootw, const float* __restrict__ initw,
    const float* __restrict__ abias, float* __restrict__ RI)
{
    __shared__ float At[32 * 65];
    __shared__ float Bl[32 * 64];
    const int tid = threadIdx.x;
    const int r0 = blockIdx.x * 64, c0 = blockIdx.y * 64;
    const int blk = c0 >> 7;
    const int gb = c0 & 127;
    const float* bsrc = (blk < 18) ? (rootw + (long)blk * FIN * 128) : (initw + (long)(blk - 18) * FIN * 128);
    const int tr = tid >> 4, tc = tid & 15;
    float acc[4][4] = {};
    for (int f0 = 0; f0 < FIN; f0 += 32) {
        __syncthreads();
        for (int s = tid; s < 64 * 32; s += 256) {
            const int r = s >> 5, kk = s & 31; const int f = f0 + kk;
            At[kk * 65 + r] = (f < FIN) ? xi[(long)(r0 + r) * FIN + f] : 0.f;
        }
        for (int s = tid; s < 32 * 64; s += 256) {
            const int kk = s >> 6, cc = s & 63; const int f = f0 + kk;
            Bl[s] = (f < FIN) ? bsrc[(long)f * 128 + gb + cc] : 0.f;
        }
        __syncthreads();
#pragma unroll 8
        for (int kk = 0; kk < 32; ++kk) {
            const float4 a4 = *(const float4*)&At[kk * 65 + tr * 4];
            const float4 b4 = *(const float4*)&Bl[kk * 64 + tc * 4];
            const float av[4] = {a4.x, a4.y, a4.z, a4.w};
            const float bv[4] = {b4.x, b4.y, b4.z, b4.w};
#pragma unroll
            for (int m = 0; m < 4; ++m)
#pragma unroll
                for (int n = 0; n < 4; ++n) acc[m][n] = fmaf(av[m], bv[n], acc[m][n]);
        }
    }
    float4 bq = {0.f, 0.f, 0.f, 0.f};
    if (blk < 18) bq = *(const float4*)&abias[c0 + tc * 4];
#pragma unroll
    for (int m = 0; m < 4; ++m) {
        float4 o4 = {acc[m][0] + bq.x, acc[m][1] + bq.y, acc[m][2] + bq.z, acc[m][3] + bq.w};
        *(float4*)&RI[(long)(r0 + tr * 4 + m) * RICOLS + c0 + tc * 4] = o4;
    }
}

// ---------------- full ARMA recurrence per (graph, stack): X0 init + 5 steps + mean into G ----------------
__global__ __launch_bounds__(512) void arma_all(const float* __restrict__ RI,
    const float* __restrict__ armaw, float* __restrict__ G)
{
    __shared__ float X0[NA * 128];
    __shared__ float X1[NA * 128];
    __shared__ float Wl[128 * 128];
    const int bid = blockIdx.x;
    const int g = bid / 3, k = bid % 3;
    const int tid = threadIdx.x;
    const size_t rbase = (size_t)g * NA;

    for (int s = tid; s < NA * 128; s += 512) {
        const int a = s >> 7, o = s & 127;
        float v = RI[(rbase + a) * RICOLS + k * 128 + o];
        if (a >= 2) v += RI[(rbase + a - 1) * RICOLS + (18 + k) * 128 + o];
        X0[s] = fmaxf(v, 0.f);
    }
    float* cur = X0;
    float* nxt = X1;
    const int q = tid & 31;        // o-quad: outs q*4..q*4+3
    const int rh = tid >> 5;       // 0..15
    for (int t = 1; t <= 5; ++t) {
        __syncthreads();           // prior writes/reads settled
        const float* W = armaw + (size_t)((t - 1) * 3 + k) * 16384;
        for (int s = tid; s < 4096; s += 512) ((float4*)Wl)[s] = ((const float4*)W)[s];
        __syncthreads();
        for (int a = rh; a < NA; a += 16) {
            float4 acc = {0.f, 0.f, 0.f, 0.f};
            if (a >= 2) {
                const float* xr = cur + (a - 1) * 128;
#pragma unroll 8
                for (int f0 = 0; f0 < 128; f0 += 4) {
                    const float4 xv = *(const float4*)(xr + f0);
                    const float4 w0 = *(const float4*)&Wl[(f0 + 0) * 128 + q * 4];
                    const float4 w1 = *(const float4*)&Wl[(f0 + 1) * 128 + q * 4];
                    const float4 w2 = *(const float4*)&Wl[(f0 + 2) * 128 + q * 4];
                    const float4 w3 = *(const float4*)&Wl[(f0 + 3) * 128 + q * 4];
                    acc.x = fmaf(xv.x, w0.x, acc.x); acc.y = fmaf(xv.x, w0.y, acc.y);
                    acc.z = fmaf(xv.x, w0.z, acc.z); acc.w = fmaf(xv.x, w0.w, acc.w);
                    acc.x = fmaf(xv.y, w1.x, acc.x); acc.y = fmaf(xv.y, w1.y, acc.y);
                    acc.z = fmaf(xv.y, w1.z, acc.z); acc.w = fmaf(xv.y, w1.w, acc.w);
                    acc.x = fmaf(xv.z, w2.x, acc.x); acc.y = fmaf(xv.z, w2.y, acc.y);
                    acc.z = fmaf(xv.z, w2.z, acc.z); acc.w = fmaf(xv.z, w2.w, acc.w);
                    acc.x = fmaf(xv.w, w3.x, acc.x); acc.y = fmaf(xv.w, w3.y, acc.y);
                    acc.z = fmaf(xv.w, w3.z, acc.z); acc.w = fmaf(xv.w, w3.w, acc.w);
                }
            }
            const float4 rv = *(const float4*)&RI[(rbase + a) * RICOLS + (t * 3 + k) * 128 + q * 4];
            float4 ov = {fmaxf(acc.x + rv.x, 0.f), fmaxf(acc.y + rv.y, 0.f),
                         fmaxf(acc.z + rv.z, 0.f), fmaxf(acc.w + rv.w, 0.f)};
            *(float4*)(nxt + a * 128 + q * 4) = ov;
        }
        float* tmp = cur; cur = nxt; nxt = tmp;
    }
    __syncthreads();
    for (int s = tid; s < NA * 128; s += 512)
        atomicAdd(&G[rbase * 128 + s], cur[s] * (1.f / 3.f));
}

// ---------------- final: aa-attention over G + MLP ----------------
__global__ __launch_bounds__(256) void final_k(const float* __restrict__ G,
    const float* __restrict__ waa, const float* __restrict__ baa,
    const float* __restrict__ w1, const float* __restrict__ b1,
    const float* __restrict__ w2, const float* __restrict__ b2,
    const float* __restrict__ w3, const float* __restrict__ b3,
    const float* __restrict__ w4, const float* __restrict__ b4, float* __restrict__ out)
{
    __shared__ float gl[50 * 129];
    __shared__ float sc[64];
    __shared__ float pl[128];
    __shared__ float h1l[64], h2l[32], h3l[16];
    __shared__ float wl[128];
    const int b = blockIdx.x, tid = threadIdx.x;
    for (int s = tid; s < 50 * 128; s += 256) {
        const int a = s >> 7, o = s & 127;
        gl[a * 129 + o] = fmaxf(G[((size_t)b * 50 + a) * 128 + o], 0.f);
    }
    if (tid < 128) wl[tid] = waa[tid];
    __syncthreads();
    if (tid < 50) {
        float acc = baa[0];
        for (int f = 0; f < 128; ++f) acc = fmaf(gl[tid * 129 + f], wl[f], acc);
        sc[tid] = acc;
    }
    __syncthreads();
    if (tid < 64) {
        const float v = (tid < 50) ? sc[tid] : -1e30f;
        float m = v;
        for (int d = 32; d; d >>= 1) m = fmaxf(m, __shfl_xor(m, d));
        const float e = (tid < 50) ? expf(v - m) : 0.f;
        float ssum = e;
        for (int d = 32; d; d >>= 1) ssum += __shfl_xor(ssum, d);
        if (tid < 50) sc[tid] = e / ssum;
    }
    __syncthreads();
    if (tid < 128) {
        float acc = 0.f;
        for (int a = 0; a < 50; ++a) acc = fmaf(sc[a], gl[a * 129 + tid], acc);
        pl[tid] = acc;
    }
    __syncthreads();
    if (tid < 64) {
        float acc = b1[tid];
        for (int f = 0; f < 128; ++f) acc = fmaf(pl[f], w1[f * 64 + tid], acc);
        h1l[tid] = fmaxf(acc, 0.f);
    }
    __syncthreads();
    if (tid < 32) {
        float acc = b2[tid];
        for (int f = 0; f < 64; ++f) acc = fmaf(h1l[f], w2[f * 32 + tid], acc);
        h2l[tid] = fmaxf(acc, 0.f);
    }
    __syncthreads();
    if (tid < 16) {
        float acc = b3[tid];
        for (int f = 0; f < 32; ++f) acc = fmaf(h2l[f], w3[f * 16 + tid], acc);
        h3l[tid] = fmaxf(acc, 0.f);
    }
    __syncthreads();
    if (tid == 0) {
        float acc = b4[0];
        for (int f = 0; f < 16; ++f) acc = fmaf(h3l[f], w4[f], acc);
        out[b] = acc;
    }
}

extern "C" void kernel_launch(void* const* d_in, const int* in_sizes, int n_in,
                              void* d_out, int out_size, void* d_ws, size_t ws_size,
                              hipStream_t stream) {
    const float* x     = (const float*)d_in[0];
    const int*   eidx  = (const int*)d_in[1];
    const float* ea    = (const float*)d_in[2];
    const float* aaf   = (const float*)d_in[4];
    const float* we1   = (const float*)d_in[5];
    const float* be1   = (const float*)d_in[6];
    const float* root1 = (const float*)d_in[7];
    const float* bias1 = (const float*)d_in[8];
    const float* we2   = (const float*)d_in[9];
    const float* be2   = (const float*)d_in[10];
    const float* root2 = (const float*)d_in[11];
    const float* bias2 = (const float*)d_in[12];
    const float* waw   = (const float*)d_in[13];
    const float* wab   = (const float*)d_in[14];
    const float* initw = (const float*)d_in[15];
    const float* armaw = (const float*)d_in[16];
    const float* rootw = (const float*)d_in[17];
    const float* abias = (const float*)d_in[18];
    const float* waa   = (const float*)d_in[19];
    const float* baa   = (const float*)d_in[20];
    const float* w1    = (const float*)d_in[21];
    const float* b1    = (const float*)d_in[22];
    const float* w2    = (const float*)d_in[23];
    const float* b2    = (const float*)d_in[24];
    const float* w3    = (const float*)d_in[25];
    const float* b3    = (const float*)d_in[26];
    const float* w4    = (const float*)d_in[27];
    const float* b4    = (const float*)d_in[28];
    float* out = (float*)d_out;

    const int* src = eidx;
    const int* dst = eidx + N_EDGES;

    char* ws = (char*)d_ws;
    size_t off = 0;
    float* h1     = (float*)(ws + off); off += (size_t)N_NODES * 64 * 4;
    float* h2     = (float*)(ws + off); off += (size_t)N_NODES * 64 * 4;
    float* xi     = (float*)(ws + off); off += (size_t)1600 * FIN * 4;
    float* RI     = (float*)(ws + off); off += (size_t)1600 * RICOLS * 4;
    float* G      = (float*)(ws + off); off += (size_t)1600 * 128 * 4;
    ushort* wt1h  = (ushort*)(ws + off); off += (size_t)17 * 8 * 64 * 8 * 2;
    ushort* wt1l  = (ushort*)(ws + off); off += (size_t)17 * 8 * 64 * 8 * 2;
    ushort* wt2h  = (ushort*)(ws + off); off += (size_t)17 * 8 * 64 * 8 * 2;
    ushort* wt2l  = (ushort*)(ws + off); off += (size_t)17 * 8 * 64 * 8 * 2;

    // weights -> bf16 hi/lo fragment layout (both convs, one launch)
    prep_w2<<<68, 256, 0, stream>>>(we1, be1, we2, be2, wt1h, wt1l, wt2h, wt2l);

    // conv1 (relu deferred to consumers)
    root_gemm<0><<<N_NODES / 64, 256, 0, stream>>>(x, root1, bias1, h1);
    edge_conv_mfma<0><<<N_EDGES / TE, 256, 0, stream>>>(x, ea, src, dst, wt1h, wt1l, h1);
    // conv2 (reads relu(h1) on load)
    root_gemm<1><<<N_NODES / 64, 256, 0, stream>>>(h1, root2, bias2, h2);
    edge_conv_mfma<1><<<N_EDGES / TE, 256, 0, stream>>>(h1, ea, src, dst, wt2h, wt2l, h2);
    // fused attention pooling -> xi
    pool_k<<<NB, 256, 0, stream>>>(h2, waw, wab, aaf, xi);
    // ARMA
    ri_gemm<<<dim3(25, 42), 256, 0, stream>>>(xi, rootw, initw, abias, RI);
    hipMemsetAsync(G, 0, (size_t)1600 * 128 * 4, stream);
    arma_all<<<NB * 3, 512, 0, stream>>>(RI, armaw, G);
    // readout + MLP
    final_k<<<NB, 256, 0, stream>>>(G, waa, baa, w1, b1, w2, b2, w3, b3, w4, b4, out);
}

// Round 7
// 347.864 us; speedup vs baseline: 1.4132x; 1.0728x over previous
//
#include <hip/hip_runtime.h>

#define N_NODES 80000
#define N_EDGES 64000
#define NB      32
#define NG      2500
#define NA      50
#define EDIM    16
#define FIN     159      // H2(64) + AF(95)
#define HG      128
#define RICOLS  2688     // 21 blocks of 128: 18 root(t,k) + 3 init(k)

typedef __attribute__((ext_vector_type(8))) short bf16x8;
typedef __attribute__((ext_vector_type(4))) float f32x4;

__device__ inline ushort rne_bf16(float f) {
    union { float f; unsigned u; } v; v.f = f;
    const unsigned r = v.u + 0x7fffu + ((v.u >> 16) & 1u);
    return (ushort)(r >> 16);
}
__device__ inline float bf16_to_f32(ushort h) {
    union { unsigned u; float f; } v; v.u = ((unsigned)h) << 16;
    return v.f;
}
__device__ __forceinline__ void gl_lds16(const void* gsrc, void* ldst) {
    __builtin_amdgcn_global_load_lds(
        (const __attribute__((address_space(1))) unsigned int*)gsrc,
        (__attribute__((address_space(3))) unsigned int*)ldst, 16, 0, 0);
}

// ---------------- weight prep (both convs): -> bf16 hi/lo fragments ----------------
__global__ __launch_bounds__(256) void prep_w2(const float* __restrict__ we1, const float* __restrict__ be1,
    const float* __restrict__ we2, const float* __restrict__ be2,
    ushort* __restrict__ w1h, ushort* __restrict__ w1l, ushort* __restrict__ w2h, ushort* __restrict__ w2l)
{
    int idx = blockIdx.x * 256 + threadIdx.x;
    const int half = (idx >= 17 * 8 * 64) ? 1 : 0;
    if (half) idx -= 17 * 8 * 64;
    if (idx >= 17 * 8 * 64) return;
    const float* we = half ? we2 : we1;
    const float* be = half ? be2 : be1;
    ushort* Wh = half ? w2h : w1h;
    ushort* Wlo = half ? w2l : w1l;
    const int l = idx & 63;
    const int slot = (idx >> 6) & 7;
    const int j = idx >> 9;
    const int n = slot >> 1, kq = slot & 1;
    const int o = n * 16 + (l & 15);
    const int i0 = kq * 32 + (l >> 4) * 8;
    ushort th[8], tl[8];
#pragma unroll
    for (int t = 0; t < 8; ++t) {
        const int i = i0 + t;
        const float f = (j < 16) ? we[j * 4096 + i * 64 + o] : be[i * 64 + o];
        const ushort hi = rne_bf16(f);
        th[t] = hi;
        tl[t] = rne_bf16(f - bf16_to_f32(hi));
    }
    *(uint4*)(Wh + (size_t)idx * 8) = *(const uint4*)th;
    *(uint4*)(Wlo + (size_t)idx * 8) = *(const uint4*)tl;
}

// ---------------- root GEMM: out[n,:] = relu?(in[n,:]) @ W(64x64) + bias ----------------
template<int RELU>
__global__ __launch_bounds__(256) void root_gemm(const float* __restrict__ in,
    const float* __restrict__ w, const float* __restrict__ bias, float* __restrict__ out)
{
    __shared__ float At[64 * 65];
    __shared__ float Wl[64 * 64];
    __shared__ float bl[64];
    const int tid = threadIdx.x;
    const int r0 = blockIdx.x * 64;
    for (int s = tid; s < 4096; s += 256) {
        int r = s >> 6, c = s & 63;
        float v = in[(r0 + r) * 64 + c];
        if (RELU) v = fmaxf(v, 0.f);
        At[c * 65 + r] = v;
    }
    for (int s = tid; s < 4096; s += 256) Wl[s] = w[s];
    if (tid < 64) bl[tid] = bias[tid];
    __syncthreads();
    const int tr = tid >> 4, tc = tid & 15;
    float acc[4][4] = {};
#pragma unroll 8
    for (int i = 0; i < 64; ++i) {
        const float4 a4 = *(const float4*)&At[i * 65 + tr * 4];
        const float4 b4 = *(const float4*)&Wl[i * 64 + tc * 4];
        const float av[4] = {a4.x, a4.y, a4.z, a4.w};
        const float bv[4] = {b4.x, b4.y, b4.z, b4.w};
#pragma unroll
        for (int m = 0; m < 4; ++m)
#pragma unroll
            for (int n = 0; n < 4; ++n) acc[m][n] = fmaf(av[m], bv[n], acc[m][n]);
    }
    const float4 bq = *(const float4*)&bl[tc * 4];
#pragma unroll
    for (int m = 0; m < 4; ++m) {
        float4 o4 = {acc[m][0] + bq.x, acc[m][1] + bq.y, acc[m][2] + bq.z, acc[m][3] + bq.w};
        *(float4*)&out[(r0 + tr * 4 + m) * 64 + tc * 4] = o4;
    }
}

// ---------------- NNConv edge kernel: bf16x3 MFMA, B in LDS via global_load_lds dbuf ----------------
#define TE 128
template<int RELU>
__global__ __launch_bounds__(256) void edge_conv_mfma(const float* __restrict__ h,
    const float* __restrict__ ea, const int* __restrict__ src, const int* __restrict__ dst,
    const ushort* __restrict__ Whi, const ushort* __restrict__ Wlo, float* __restrict__ agg)
{
    __shared__ ushort Bst[2][8192];
    __shared__ float  EAt[17 * 132];
    const int tid = threadIdx.x;
    const int e0 = blockIdx.x * TE;
    const int wv = tid >> 6, l = tid & 63;

#pragma unroll
    for (int i = 0; i < 4; ++i) {
        const int c = wv * 4 + i;
        const ushort* gs = (c < 8) ? (Whi + ((size_t)c * 64 + l) * 8)
                                   : (Wlo + ((size_t)(c - 8) * 64 + l) * 8);
        gl_lds16(gs, (char*)(&Bst[0][0]) + c * 1024);
    }
    for (int s = tid; s < TE * 16; s += 256) {
        const int le = s >> 4, j = s & 15;
        EAt[j * 132 + le] = ea[(size_t)(e0 + le) * 16 + j];
    }
    if (tid < TE) EAt[16 * 132 + tid] = 1.0f;

    bf16x8 ah[2][2], al[2][2];
#pragma unroll
    for (int m = 0; m < 2; ++m) {
        const int erow = wv * 32 + m * 16 + (l & 15);
        const int nd = src[e0 + erow];
        const float4* hp = (const float4*)(h + (size_t)nd * 64);
#pragma unroll
        for (int kq = 0; kq < 2; ++kq) {
            const int q0 = kq * 8 + (l >> 4) * 2;
            const float4 v0 = hp[q0], v1 = hp[q0 + 1];
            const float fv[8] = {v0.x, v0.y, v0.z, v0.w, v1.x, v1.y, v1.z, v1.w};
            ushort th[8], tl[8];
#pragma unroll
            for (int t = 0; t < 8; ++t) {
                const float f = RELU ? fmaxf(fv[t], 0.f) : fv[t];
                th[t] = rne_bf16(f);
                tl[t] = rne_bf16(f - bf16_to_f32(th[t]));
            }
            ah[m][kq] = *(const bf16x8*)th;
            al[m][kq] = *(const bf16x8*)tl;
        }
    }
    __syncthreads();

    f32x4 msg[2][4];
#pragma unroll
    for (int m = 0; m < 2; ++m)
#pragma unroll
        for (int n = 0; n < 4; ++n) msg[m][n] = (f32x4)0.f;

#pragma unroll 1
    for (int j = 0; j < 17; ++j) {
        const int cur = j & 1;
        if (j < 16) {
#pragma unroll
            for (int i = 0; i < 4; ++i) {
                const int c = wv * 4 + i;
                const ushort* gs = (c < 8) ? (Whi + ((size_t)((j + 1) * 8 + c) * 64 + l) * 8)
                                           : (Wlo + ((size_t)((j + 1) * 8 + (c - 8)) * 64 + l) * 8);
                gl_lds16(gs, (char*)(&Bst[cur ^ 1][0]) + c * 1024);
            }
        }
        f32x4 eam[2];
        eam[0] = *(const f32x4*)&EAt[j * 132 + wv * 32 + (l >> 4) * 4];
        eam[1] = *(const f32x4*)&EAt[j * 132 + wv * 32 + 16 + (l >> 4) * 4];
#pragma unroll
        for (int n = 0; n < 4; ++n) {
            const char* bb = (const char*)(&Bst[cur][0]);
            const bf16x8 bh0 = *(const bf16x8*)(bb + ((n * 2 + 0) * 64 + l) * 16);
            const bf16x8 bh1 = *(const bf16x8*)(bb + ((n * 2 + 1) * 64 + l) * 16);
            const bf16x8 bl0 = *(const bf16x8*)(bb + 8192 + ((n * 2 + 0) * 64 + l) * 16);
            const bf16x8 bl1 = *(const bf16x8*)(bb + 8192 + ((n * 2 + 1) * 64 + l) * 16);
#pragma unroll
            for (int m = 0; m < 2; ++m) {
                f32x4 t = __builtin_amdgcn_mfma_f32_16x16x32_bf16(ah[m][0], bh0, (f32x4)0.f, 0, 0, 0);
                t = __builtin_amdgcn_mfma_f32_16x16x32_bf16(ah[m][1], bh1, t, 0, 0, 0);
                t = __builtin_amdgcn_mfma_f32_16x16x32_bf16(ah[m][0], bl0, t, 0, 0, 0);
                t = __builtin_amdgcn_mfma_f32_16x16x32_bf16(ah[m][1], bl1, t, 0, 0, 0);
                t = __builtin_amdgcn_mfma_f32_16x16x32_bf16(al[m][0], bh0, t, 0, 0, 0);
                t = __builtin_amdgcn_mfma_f32_16x16x32_bf16(al[m][1], bh1, t, 0, 0, 0);
                msg[m][n] += eam[m] * t;
            }
        }
        __syncthreads();
    }

#pragma unroll
    for (int m = 0; m < 2; ++m)
#pragma unroll
        for (int r = 0; r < 4; ++r) {
            const int erow = wv * 32 + m * 16 + (l >> 4) * 4 + r;
            const size_t d = (size_t)dst[e0 + erow] * 64;
#pragma unroll
            for (int n = 0; n < 4; ++n)
                atomicAdd(&agg[d + n * 16 + (l & 15)], msg[m][n][r]);
        }
}

// ---------------- atom attention scores (relu on load) ----------------
__global__ __launch_bounds__(256) void scores_k(const float* __restrict__ h2,
    const float* __restrict__ w, const float* __restrict__ b, float* __restrict__ sc)
{
    __shared__ float wl[64];
    if (threadIdx.x < 64) wl[threadIdx.x] = w[threadIdx.x];
    __syncthreads();
    const int n = blockIdx.x * 256 + threadIdx.x;
    if (n < N_NODES) {
        float acc = b[0];
        const float4* hp = (const float4*)(h2 + (long)n * 64);
#pragma unroll
        for (int q = 0; q < 16; ++q) {
            const float4 v = hp[q];
            acc = fmaf(fmaxf(v.x, 0.f), wl[q * 4 + 0], acc); acc = fmaf(fmaxf(v.y, 0.f), wl[q * 4 + 1], acc);
            acc = fmaf(fmaxf(v.z, 0.f), wl[q * 4 + 2], acc); acc = fmaf(fmaxf(v.w, 0.f), wl[q * 4 + 3], acc);
        }
        sc[n] = acc;
    }
}

// ---------------- per-graph softmax over atoms ----------------
__global__ __launch_bounds__(256) void softmax_k(const float* __restrict__ sc, float* __restrict__ attn)
{
    __shared__ float red[256];
    const int g = blockIdx.x, tid = threadIdx.x;
    const float* s = sc + (long)g * NG;
    float m = -1e30f;
    for (int a = tid; a < NG; a += 256) m = fmaxf(m, s[a]);
    red[tid] = m; __syncthreads();
    for (int st = 128; st; st >>= 1) { if (tid < st) red[tid] = fmaxf(red[tid], red[tid + st]); __syncthreads(); }
    const float mx = red[0]; __syncthreads();
    float sum = 0.f;
    for (int a = tid; a < NG; a += 256) sum += expf(s[a] - mx);
    red[tid] = sum; __syncthreads();
    for (int st = 128; st; st >>= 1) { if (tid < st) red[tid] += red[tid + st]; __syncthreads(); }
    const float inv = 1.0f / red[0];
    for (int a = tid; a < NG; a += 256) attn[(long)g * NG + a] = expf(s[a] - mx) * inv;
}

// ---------------- residue pooling + xi concat (relu on load) ----------------
__global__ __launch_bounds__(256) void amino_k(const float* __restrict__ h2,
    const float* __restrict__ attn, const float* __restrict__ aa, float* __restrict__ xi)
{
    const int tid = threadIdx.x;
    const int r = blockIdx.x * 4 + (tid >> 6);
    const int o = tid & 63;
    const int g = r / NA, ar = r % NA;
    const long base = (long)g * NG + ar * 50;
    float acc = 0.f;
#pragma unroll 10
    for (int a = 0; a < 50; ++a) acc = fmaf(attn[base + a], fmaxf(h2[(base + a) * 64 + o], 0.f), acc);
    xi[(long)r * FIN + o] = acc;
    for (int s = tid; s < 4 * 95; s += 256) {
        const int lr = s / 95, f = s % 95;
        const int rr = blockIdx.x * 4 + lr;
        xi[(long)rr * FIN + 64 + f] = aa[(long)rr * 95 + f];
    }
}

// ---------------- RI GEMM: [1600,159] @ [159,2688] (+bias on root cols) ----------------
__global__ __launch_bounds__(256) void ri_gemm(const float* __restrict__ xi,
    const float* __restrict__ rootw, const float* __restrict__ initw,
    const float* __restrict__ abias, float* __restrict__ RI)
{
    __shared__ float At[32 * 65];
    __shared__ float Bl[32 * 64];
    const int tid = threadIdx.x;
    const int r0 = blockIdx.x * 64, c0 = blockIdx.y * 64;
    const int blk = c0 >> 7;
    const int gb = c0 & 127;
    const float* bsrc = (blk < 18) ? (rootw + (long)blk * FIN * 128) : (initw + (long)(blk - 18) * FIN * 128);
    const int tr = tid >> 4, tc = tid & 15;
    float acc[4][4] = {};
    for (int f0 = 0; f0 < FIN; f0 += 32) {
        __syncthreads();
        for (int s = tid; s < 64 * 32; s += 256) {
            const int r = s >> 5, kk = s & 31; const int f = f0 + kk;
            At[kk * 65 + r] = (f < FIN) ? xi[(long)(r0 + r) * FIN + f] : 0.f;
        }
        for (int s = tid; s < 32 * 64; s += 256) {
            const int kk = s >> 6, cc = s & 63; const int f = f0 + kk;
            Bl[s] = (f < FIN) ? bsrc[(long)f * 128 + gb + cc] : 0.f;
        }
        __syncthreads();
#pragma unroll 8
        for (int kk = 0; kk < 32; ++kk) {
            const float4 a4 = *(const float4*)&At[kk * 65 + tr * 4];
            const float4 b4 = *(const float4*)&Bl[kk * 64 + tc * 4];
            const float av[4] = {a4.x, a4.y, a4.z, a4.w};
            const float bv[4] = {b4.x, b4.y, b4.z, b4.w};
#pragma unroll
            for (int m = 0; m < 4; ++m)
#pragma unroll
                for (int n = 0; n < 4; ++n) acc[m][n] = fmaf(av[m], bv[n], acc[m][n]);
        }
    }
    float4 bq = {0.f, 0.f, 0.f, 0.f};
    if (blk < 18) bq = *(const float4*)&abias[c0 + tc * 4];
#pragma unroll
    for (int m = 0; m < 4; ++m) {
        float4 o4 = {acc[m][0] + bq.x, acc[m][1] + bq.y, acc[m][2] + bq.z, acc[m][3] + bq.w};
        *(float4*)&RI[(long)(r0 + tr * 4 + m) * RICOLS + c0 + tc * 4] = o4;
    }
}

// ---------------- ARMA: halo-split halves, 4x4 register blocking, per-k G banks ----------------
// bid -> g = bid/6, k = (bid%6)>>1, half = bid&1. half0 holds rows [0,30) writes [0,25);
// half1 holds rows [20,50) writes [25,50). Valid region shrinks 1 row/step = dependency depth.
__global__ __launch_bounds__(256) void arma_all(const float* __restrict__ RI,
    const float* __restrict__ armaw, float* __restrict__ G)
{
    __shared__ float X[2][32 * 128];   // 16 KB each
    __shared__ float Wl[128 * 128];    // 64 KB
    const int bid = blockIdx.x;
    const int g = bid / 6, k = (bid % 6) >> 1, half = bid & 1;
    const int tid = threadIdx.x;
    const int r0 = half ? 20 : 0;
    const size_t rbase = (size_t)g * NA;

    // X0 rows r0..r0+29
    for (int s = tid; s < 30 * 128; s += 256) {
        const int a = r0 + (s >> 7), o = s & 127;
        float v = RI[(rbase + a) * RICOLS + k * 128 + o];
        if (a >= 2) v += RI[(rbase + a - 1) * RICOLS + (18 + k) * 128 + o];
        X[0][s] = fmaxf(v, 0.f);
    }
    int cur = 0;
    const int rg = tid >> 5;       // 0..7 -> local rows rg*4..rg*4+3
    const int cg = tid & 31;       // cols cg*4..cg*4+3
    for (int t = 1; t <= 5; ++t) {
        __syncthreads();
        const float* W = armaw + (size_t)((t - 1) * 3 + k) * 16384;
        for (int s = tid; s < 4096; s += 256) ((float4*)Wl)[s] = ((const float4*)W)[s];
        __syncthreads();
        float acc[4][4] = {};
#pragma unroll 4
        for (int f0 = 0; f0 < 128; f0 += 4) {
            float4 wv[4];
#pragma unroll
            for (int i = 0; i < 4; ++i) wv[i] = *(const float4*)&Wl[(f0 + i) * 128 + cg * 4];
#pragma unroll
            for (int m = 0; m < 4; ++m) {
                const int lr = rg * 4 + m;
                const int pl = (lr >= 1) ? lr - 1 : 0;        // clamped (unused rows)
                const float4 xv = *(const float4*)&X[cur][pl * 128 + f0];
#pragma unroll
                for (int n = 0; n < 4; ++n) {
                    acc[m][n] = fmaf(xv.x, ((const float*)&wv[0])[n], acc[m][n]);
                    acc[m][n] = fmaf(xv.y, ((const float*)&wv[1])[n], acc[m][n]);
                    acc[m][n] = fmaf(xv.z, ((const float*)&wv[2])[n], acc[m][n]);
                    acc[m][n] = fmaf(xv.w, ((const float*)&wv[3])[n], acc[m][n]);
                }
            }
        }
        __syncthreads();   // done reading X[cur]
#pragma unroll
        for (int m = 0; m < 4; ++m) {
            const int lr = rg * 4 + m;
            if (lr < 30) {
                const int a = r0 + lr;
                const bool prop = (a >= 2) && (lr >= 1);
                const float4 rv = *(const float4*)&RI[(rbase + a) * RICOLS + (t * 3 + k) * 128 + cg * 4];
                float4 ov;
                ov.x = fmaxf((prop ? acc[m][0] : 0.f) + rv.x, 0.f);
                ov.y = fmaxf((prop ? acc[m][1] : 0.f) + rv.y, 0.f);
                ov.z = fmaxf((prop ? acc[m][2] : 0.f) + rv.z, 0.f);
                ov.w = fmaxf((prop ? acc[m][3] : 0.f) + rv.w, 0.f);
                *(float4*)&X[cur ^ 1][lr * 128 + cg * 4] = ov;
            }
        }
        cur ^= 1;
    }
    __syncthreads();
    // write own rows to per-k bank
    const int w0 = half ? 25 : 0;
    for (int s = tid; s < 25 * 128; s += 256) {
        const int a = w0 + (s >> 7), o = s & 127;
        G[((size_t)k * 1600 + rbase + a) * 128 + o] = X[cur][(a - r0) * 128 + o];
    }
}

// ---------------- final: mean over k-banks + relu, aa-attention, MLP ----------------
__global__ __launch_bounds__(256) void final_k(const float* __restrict__ G,
    const float* __restrict__ waa, const float* __restrict__ baa,
    const float* __restrict__ w1, const float* __restrict__ b1,
    const float* __restrict__ w2, const float* __restrict__ b2,
    const float* __restrict__ w3, const float* __restrict__ b3,
    const float* __restrict__ w4, const float* __restrict__ b4, float* __restrict__ out)
{
    __shared__ float gl[50 * 129];
    __shared__ float sc[64];
    __shared__ float pl[128];
    __shared__ float h1l[64], h2l[32], h3l[16];
    __shared__ float wl[128];
    const int b = blockIdx.x, tid = threadIdx.x;
    for (int s = tid; s < 50 * 128; s += 256) {
        const int a = s >> 7, o = s & 127;
        const size_t r = ((size_t)b * 50 + a) * 128 + o;
        const float v = (G[r] + G[(size_t)1600 * 128 + r] + G[(size_t)2 * 1600 * 128 + r]) * (1.f / 3.f);
        gl[a * 129 + o] = fmaxf(v, 0.f);
    }
    if (tid < 128) wl[tid] = waa[tid];
    __syncthreads();
    if (tid < 50) {
        float acc = baa[0];
        for (int f = 0; f < 128; ++f) acc = fmaf(gl[tid * 129 + f], wl[f], acc);
        sc[tid] = acc;
    }
    __syncthreads();
    if (tid < 64) {
        const float v = (tid < 50) ? sc[tid] : -1e30f;
        float m = v;
        for (int d = 32; d; d >>= 1) m = fmaxf(m, __shfl_xor(m, d));
        const float e = (tid < 50) ? expf(v - m) : 0.f;
        float ssum = e;
        for (int d = 32; d; d >>= 1) ssum += __shfl_xor(ssum, d);
        if (tid < 50) sc[tid] = e / ssum;
    }
    __syncthreads();
    if (tid < 128) {
        float acc = 0.f;
        for (int a = 0; a < 50; ++a) acc = fmaf(sc[a], gl[a * 129 + tid], acc);
        pl[tid] = acc;
    }
    __syncthreads();
    if (tid < 64) {
        float acc = b1[tid];
        for (int f = 0; f < 128; ++f) acc = fmaf(pl[f], w1[f * 64 + tid], acc);
        h1l[tid] = fmaxf(acc, 0.f);
    }
    __syncthreads();
    if (tid < 32) {
        float acc = b2[tid];
        for (int f = 0; f < 64; ++f) acc = fmaf(h1l[f], w2[f * 32 + tid], acc);
        h2l[tid] = fmaxf(acc, 0.f);
    }
    __syncthreads();
    if (tid < 16) {
        float acc = b3[tid];
        for (int f = 0; f < 32; ++f) acc = fmaf(h2l[f], w3[f * 16 + tid], acc);
        h3l[tid] = fmaxf(acc, 0.f);
    }
    __syncthreads();
    if (tid == 0) {
        float acc = b4[0];
        for (int f = 0; f < 16; ++f) acc = fmaf(h3l[f], w4[f], acc);
        out[b] = acc;
    }
}

extern "C" void kernel_launch(void* const* d_in, const int* in_sizes, int n_in,
                              void* d_out, int out_size, void* d_ws, size_t ws_size,
                              hipStream_t stream) {
    const float* x     = (const float*)d_in[0];
    const int*   eidx  = (const int*)d_in[1];
    const float* ea    = (const float*)d_in[2];
    const float* aaf   = (const float*)d_in[4];
    const float* we1   = (const float*)d_in[5];
    const float* be1   = (const float*)d_in[6];
    const float* root1 = (const float*)d_in[7];
    const float* bias1 = (const float*)d_in[8];
    const float* we2   = (const float*)d_in[9];
    const float* be2   = (const float*)d_in[10];
    const float* root2 = (const float*)d_in[11];
    const float* bias2 = (const float*)d_in[12];
    const float* waw   = (const float*)d_in[13];
    const float* wab   = (const float*)d_in[14];
    const float* initw = (const float*)d_in[15];
    const float* armaw = (const float*)d_in[16];
    const float* rootw = (const float*)d_in[17];
    const float* abias = (const float*)d_in[18];
    const float* waa   = (const float*)d_in[19];
    const float* baa   = (const float*)d_in[20];
    const float* w1    = (const float*)d_in[21];
    const float* b1    = (const float*)d_in[22];
    const float* w2    = (const float*)d_in[23];
    const float* b2    = (const float*)d_in[24];
    const float* w3    = (const float*)d_in[25];
    const float* b3    = (const float*)d_in[26];
    const float* w4    = (const float*)d_in[27];
    const float* b4    = (const float*)d_in[28];
    float* out = (float*)d_out;

    const int* src = eidx;
    const int* dst = eidx + N_EDGES;

    char* ws = (char*)d_ws;
    size_t off = 0;
    float* h1     = (float*)(ws + off); off += (size_t)N_NODES * 64 * 4;
    float* h2     = (float*)(ws + off); off += (size_t)N_NODES * 64 * 4;
    float* scores = (float*)(ws + off); off += (size_t)N_NODES * 4;
    float* attn   = (float*)(ws + off); off += (size_t)N_NODES * 4;
    float* xi     = (float*)(ws + off); off += (size_t)1600 * FIN * 4;
    float* RI     = (float*)(ws + off); off += (size_t)1600 * RICOLS * 4;
    float* G      = (float*)(ws + off); off += (size_t)3 * 1600 * 128 * 4;
    ushort* wt1h  = (ushort*)(ws + off); off += (size_t)17 * 8 * 64 * 8 * 2;
    ushort* wt1l  = (ushort*)(ws + off); off += (size_t)17 * 8 * 64 * 8 * 2;
    ushort* wt2h  = (ushort*)(ws + off); off += (size_t)17 * 8 * 64 * 8 * 2;
    ushort* wt2l  = (ushort*)(ws + off); off += (size_t)17 * 8 * 64 * 8 * 2;

    prep_w2<<<68, 256, 0, stream>>>(we1, be1, we2, be2, wt1h, wt1l, wt2h, wt2l);

    // conv1 (relu deferred to consumers)
    root_gemm<0><<<N_NODES / 64, 256, 0, stream>>>(x, root1, bias1, h1);
    edge_conv_mfma<0><<<N_EDGES / TE, 256, 0, stream>>>(x, ea, src, dst, wt1h, wt1l, h1);
    // conv2 (reads relu(h1) on load)
    root_gemm<1><<<N_NODES / 64, 256, 0, stream>>>(h1, root2, bias2, h2);
    edge_conv_mfma<1><<<N_EDGES / TE, 256, 0, stream>>>(h1, ea, src, dst, wt2h, wt2l, h2);
    // attention pooling -> xi (wide-grid kernels)
    scores_k<<<(N_NODES + 255) / 256, 256, 0, stream>>>(h2, waw, wab, scores);
    softmax_k<<<NB, 256, 0, stream>>>(scores, attn);
    amino_k<<<1600 / 4, 256, 0, stream>>>(h2, attn, aaf, xi);
    // ARMA
    ri_gemm<<<dim3(25, 42), 256, 0, stream>>>(xi, rootw, initw, abias, RI);
    arma_all<<<NB * 6, 256, 0, stream>>>(RI, armaw, G);
    // readout + MLP
    final_k<<<NB, 256, 0, stream>>>(G, waa, baa, w1, b1, w2, b2, w3, b3, w4, b4, out);
}